// Round 1
// 183.051 us; speedup vs baseline: 1.0116x; 1.0116x over previous
//
#include <hip/hip_runtime.h>
#include <hip/hip_bf16.h>

typedef unsigned short u16;
typedef unsigned int u32;
typedef unsigned long long u64;
typedef short s8v __attribute__((ext_vector_type(8)));
typedef short s4v __attribute__((ext_vector_type(4)));
typedef __bf16 bfv8 __attribute__((ext_vector_type(8)));
typedef float f4 __attribute__((ext_vector_type(4)));

static constexpr int B = 2, D = 1024, L = 2048, H = 16, DK = 64, E = 1024;
// fold 1/sqrt(DK) and log2(e) into Q so softmax runs natively in exp2 domain
static constexpr float QSCALE = 0.125f * 1.44269504088896340736f;
static constexpr float SMB = -16.0f;       // fixed softmax bias (|s|<~10)
static constexpr float MASKB = -12000.0f;  // exp2(MASKB+s) == 0.0f exactly

#define DEV __device__ __forceinline__

DEV u16 f2bf(float f) {  // fp32 -> bf16 round-to-nearest-even
  unsigned int u = __float_as_uint(f);
  u += 0x7FFFu + ((u >> 16) & 1u);
  return (u16)(u >> 16);
}
DEV float fexp2(float x) { return __builtin_amdgcn_exp2f(x); }
DEV u32 pkbf(float a, float b) {  // packed fp32x2 -> bf16x2 (v_cvt_pk)
  __hip_bfloat162 h = __float22bfloat162_rn(float2{a, b});
  u32 r;
  __builtin_memcpy(&r, &h, 4);
  return r;
}
DEV bfv8 cat8(s4v a, s4v b) {  // concat two 4x bf16 frags -> K=32 B-frag
  s8v r;
#pragma unroll
  for (int i = 0; i < 4; ++i) {
    r[i] = a[i];
    r[i + 4] = b[i];
  }
  return __builtin_bit_cast(bfv8, r);
}
// key-permutation: LDS kt row kk holds physical key kperm(kk).
// Within each 32-key group: row s*16+q*4+r -> key q*8+s*4+r, so that the
// QK^T output quads concat directly into K=32 PV B-frags over consecutive
// physical keys (V stays in natural order).
DEV int kperm(int kk) {
  return (kk & 96) | (((kk >> 2) & 3) << 3) | (((kk >> 4) & 1) << 2) |
         (kk & 3);
}

#define GLD_LDS16(gp, lp)                                                     \
  __builtin_amdgcn_global_load_lds(                                           \
      (const __attribute__((address_space(1))) void*)(gp),                    \
      (__attribute__((address_space(3))) void*)(lp), 16, 0, 0)

// ---------- Kernel 0: fused fp32->bf16 64x64 tile transposes ----------
__global__ __launch_bounds__(256) void k_prep(
    const float* __restrict__ x, const float* __restrict__ Wq,
    const float* __restrict__ Wk, const float* __restrict__ Wv,
    const float* __restrict__ Wo, u16* __restrict__ xt, u16* __restrict__ Wt,
    u16* __restrict__ WoT) {
  __shared__ u16 t[64][67];
  const int tid = threadIdx.x;
  const int g = blockIdx.x;
  const float* src;
  u16* dst;
  int sld, dld;
  if (g < 1024) {
    const int b = g >> 9, dt = (g >> 5) & 15, lt = g & 31;
    src = x + ((size_t)b * D + dt * 64) * L + lt * 64;
    sld = L;
    dst = xt + ((size_t)b * L + lt * 64) * D + dt * 64;
    dld = D;
  } else if (g < 1792) {
    const int u = g - 1024;
    const int w = u >> 8, h = (u >> 4) & 15, dt = u & 15;
    const float* Ws = (w == 0) ? Wq : ((w == 1) ? Wk : Wv);
    src = Ws + ((size_t)h * D + dt * 64) * DK;
    sld = DK;
    dst = Wt + ((size_t)(w * H + h) * DK) * D + dt * 64;
    dld = D;
  } else {
    const int v = g - 1792;
    const int et = v >> 4, dt = v & 15;
    src = Wo + ((size_t)et * 64) * D + dt * 64;
    sld = D;
    dst = WoT + ((size_t)dt * 64) * E + et * 64;
    dld = E;
  }
  const int r = tid >> 2, c16 = (tid & 3) * 16;
#pragma unroll
  for (int j = 0; j < 16; j += 4) {
    const f4 v4 = *(const f4*)(src + (size_t)r * sld + c16 + j);
    t[r][c16 + j]     = f2bf(v4[0]);
    t[r][c16 + j + 1] = f2bf(v4[1]);
    t[r][c16 + j + 2] = f2bf(v4[2]);
    t[r][c16 + j + 3] = f2bf(v4[3]);
  }
  __syncthreads();
  s8v o0, o1;
#pragma unroll
  for (int i = 0; i < 8; ++i) {
    o0[i] = (short)t[c16 + i][r];
    o1[i] = (short)t[c16 + 8 + i][r];
  }
  *(s8v*)(dst + (size_t)r * dld + c16)     = o0;
  *(s8v*)(dst + (size_t)r * dld + c16 + 8) = o1;
}

// ---------- shared GEMM tile core: BK=64, single-buffer, 1 barrier-pair ----
// LDS tiles [rows][64] u16 (128B rows), swizzle phys_chunk = logical^(row&7).
// 16 K-iterations (vs 32 at BK=32): half the barrier/drain tax, same bytes.
template <int AR>
DEV void gemm_tile(const u16* __restrict__ A, const u16* __restrict__ Bt,
                   int arow0, int brow0, u16* As, u16* Bs,
                   f4 (&acc)[AR / 32][4]) {
  const int tid = threadIdx.x;
  const int wid = tid >> 6, lane = tid & 63;
  const int q = lane >> 4, ln = lane & 15;
  const int wr = wid >> 1, wc = wid & 1;
  const int lrow = lane >> 3;        // 0..7 (dest row & 7)
  const int lc = (lane & 7) ^ lrow;  // logical chunk for swizzled dest
  const int f0 = (q ^ (ln & 7)) * 8;        // frag phys chunk, k-step 0
  const int f1 = ((q + 4) ^ (ln & 7)) * 8;  // k-step 1
  constexpr int MT = AR / 32;

  for (int k0 = 0; k0 < 1024; k0 += 64) {
    __syncthreads();
#pragma unroll
    for (int j = 0; j < AR / 32; ++j) {  // A: 8 rows per instr
      const int rb = wid * (AR / 4) + j * 8;
      GLD_LDS16(A + (size_t)(arow0 + rb + lrow) * 1024 + k0 + lc * 8,
                As + rb * 64);
    }
#pragma unroll
    for (int j = 0; j < 4; ++j) {  // B: 128 rows
      const int rb = wid * 32 + j * 8;
      GLD_LDS16(Bt + (size_t)(brow0 + rb + lrow) * 1024 + k0 + lc * 8,
                Bs + rb * 64);
    }
    __syncthreads();
#pragma unroll
    for (int ks = 0; ks < 2; ++ks) {
      const int fc = ks ? f1 : f0;
      bfv8 af[MT], bf[4];
#pragma unroll
      for (int mt = 0; mt < MT; ++mt)
        af[mt] = *(const bfv8*)(As + (wr * (AR / 2) + mt * 16 + ln) * 64 + fc);
#pragma unroll
      for (int nt = 0; nt < 4; ++nt)
        bf[nt] = *(const bfv8*)(Bs + (wc * 64 + nt * 16 + ln) * 64 + fc);
#pragma unroll
      for (int mt = 0; mt < MT; ++mt)
#pragma unroll
        for (int nt = 0; nt < 4; ++nt)
          acc[mt][nt] = __builtin_amdgcn_mfma_f32_16x16x32_bf16(
              af[mt], bf[nt], acc[mt][nt], 0, 0, 0);
    }
  }
}

// ---------- Kernel 1: QKV projection as one GEMM ----------
__global__ __launch_bounds__(256, 3) void k_qkvg(
    const u16* __restrict__ xt, const u16* __restrict__ Wt,
    u16* __restrict__ Q, u16* __restrict__ K, u16* __restrict__ Vt) {
  __shared__ u16 As[128 * 64];  // 16 KB
  __shared__ u16 Bs[128 * 64];  // 16 KB  (32 KB total: 3 blocks/CU ok)
  const int bm = blockIdx.x, bn = blockIdx.y;
  f4 acc[4][4];
#pragma unroll
  for (int mt = 0; mt < 4; ++mt)
#pragma unroll
    for (int nt = 0; nt < 4; ++nt) acc[mt][nt] = (f4){0.f, 0.f, 0.f, 0.f};
  gemm_tile<128>(xt, Wt, bm * 128, bn * 128, As, Bs, acc);

  const int tid = threadIdx.x, wid = tid >> 6, lane = tid & 63;
  const int q = lane >> 4, ln = lane & 15;
  const int wr = wid >> 1, wc = wid & 1;
  const int h2 = bn * 2 + wc;  // 0..47
  const int wsel = h2 >> 4, h = h2 & 15;
  const int b = bm >> 4;
  const int lbase = (bm & 15) * 128 + wr * 64;
  if (wsel == 0) {
    u16* dst = Q + (size_t)(b * H + h) * L * DK;
#pragma unroll
    for (int mt = 0; mt < 4; ++mt)
#pragma unroll
      for (int nt = 0; nt < 4; ++nt)
#pragma unroll
        for (int r = 0; r < 4; ++r)
          dst[(size_t)(lbase + mt * 16 + q * 4 + r) * DK + nt * 16 + ln] =
              f2bf(acc[mt][nt][r] * QSCALE);
  } else if (wsel == 1) {
    u16* dst = K + (size_t)(b * H + h) * L * DK;
#pragma unroll
    for (int mt = 0; mt < 4; ++mt)
#pragma unroll
      for (int nt = 0; nt < 4; ++nt)
#pragma unroll
        for (int r = 0; r < 4; ++r)
          dst[(size_t)(lbase + mt * 16 + q * 4 + r) * DK + nt * 16 + ln] =
              f2bf(acc[mt][nt][r]);
  } else {
    // V: plain transpose Vt[dk][l], 4 consecutive l per lane -> 8B stores
    u16* dst = Vt + (size_t)(b * H + h) * DK * L;
#pragma unroll
    for (int mt = 0; mt < 4; ++mt)
#pragma unroll
      for (int nt = 0; nt < 4; ++nt) {
        const u64 pk = (u64)pkbf(acc[mt][nt][0], acc[mt][nt][1]) |
                       ((u64)pkbf(acc[mt][nt][2], acc[mt][nt][3]) << 32);
        *(u64*)(dst + (size_t)(nt * 16 + ln) * L + lbase + mt * 16 + q * 4) =
            pk;
      }
  }
}

// ---------- Kernel 2: flash attention, 128-key tiles ----------
// R12: 8 waves x 16 q-rows (512 thr) for 16 waves/CU (was 8); key-permuted
// kt staging so PV runs on native K=32 MFMA (was 64x mfma_16x16x16_1k).
__global__ __launch_bounds__(512, 4) void k_attn(
    const u16* __restrict__ Q, const u16* __restrict__ K,
    const u16* __restrict__ Vt, const float* __restrict__ mask,
    u16* __restrict__ Hd) {
  __shared__ u16 kt[2][128 * 64];    // [keyrow(permuted)][dk], chunk-swizzled
  __shared__ u16 vt[2][2][64 * 64];  // [half][dk][key(natural)], same swizzle
  __shared__ __align__(16) float mb[L];  // per-key bias: SMB or MASKB
  const int h = blockIdx.x, lt = blockIdx.y, b = blockIdx.z;
  const int tid = threadIdx.x;
  const int w = tid >> 6, lane = tid & 63, q = lane >> 4, ln = lane & 15;
  for (int i = tid; i < L; i += 512)
    mb[i] = (mask[(size_t)b * L + i] != 0.0f) ? SMB : MASKB;

  const int bh = b * H + h;
  const u16* Qp = Q + (size_t)bh * L * DK;
  const u16* Kp = K + (size_t)bh * L * DK;
  const u16* Vp = Vt + (size_t)bh * DK * L;
  const int lq = lt * 128 + w * 16;  // wave covers 16 q-rows

  bfv8 qf[2];
  qf[0] = *(const bfv8*)(Qp + (size_t)(lq + ln) * DK + q * 8);
  qf[1] = *(const bfv8*)(Qp + (size_t)(lq + ln) * DK + 32 + q * 8);

  const int lrow = lane >> 3;        // 0..7 (== dest row & 7)
  const int lc = (lane & 7) ^ lrow;  // logical chunk for swizzled dest
  const int c0 = (q ^ (ln & 7)) * 8;        // K-frag phys chunk, low dk half
  const int c1 = ((q + 4) ^ (ln & 7)) * 8;  // high dk half

  auto stage = [&](int m0, int bufi) {
    // kt: 128 rows, 8 waves x 16 rows, permuted key order
#pragma unroll
    for (int j = 0; j < 2; ++j) {
      const int rb = w * 16 + j * 8;
      GLD_LDS16(Kp + (size_t)(m0 + kperm(rb + lrow)) * DK + lc * 8,
                &kt[bufi][rb * 64]);
    }
    // vt: per half 64 dk-rows, 8 waves x 8 rows, natural key order
    const int fr = w * 8 + lrow;
#pragma unroll
    for (int kh = 0; kh < 2; ++kh) {
      GLD_LDS16(Vp + (size_t)fr * L + m0 + kh * 64 + lc * 8,
                &vt[bufi][kh][(w * 8) * 64]);
    }
  };

  f4 ot[4];  // O^T[dk=dt*16+q*4+r][qrow=ln]
#pragma unroll
  for (int i = 0; i < 4; ++i) ot[i] = (f4){0.f, 0.f, 0.f, 0.f};
  float lp = 0.f;  // partial row-sum (this quad's keys)

  stage(0, 0);
  for (int it = 0; it < L / 128; ++it) {
    const int m0 = it * 128;
    __syncthreads();  // buf(it&1) landed; mb ready; prev buf reads done
    if (it + 1 < L / 128) stage(m0 + 128, (it + 1) & 1);
    const int cur = it & 1;
    const u16* ktc = &kt[cur][0];

    // QK^T swapped (D[m=permuted key][n=qrow]) fused with exp2+pack.
    // Adjacent even/odd strips concat into K=32 PV B-frags (see kperm).
    s4v pbe;
    bfv8 pbx[4];
#pragma unroll
    for (int nt = 0; nt < 8; ++nt) {
      const int krow = nt * 16 + ln;  // krow&7 == ln&7: c0/c1 valid
      const bfv8 kf0 = *(const bfv8*)(ktc + krow * 64 + c0);
      const bfv8 kf1 = *(const bfv8*)(ktc + krow * 64 + c1);
      // mask bias at the PHYSICAL key held by this output quad
      const f4 mbv = *(const f4*)(mb + m0 + (nt >> 1) * 32 + (nt & 1) * 4 +
                                  q * 8);
      f4 a = mbv;  // mask bias in accumulator init
      a = __builtin_amdgcn_mfma_f32_16x16x32_bf16(kf0, qf[0], a, 0, 0, 0);
      a = __builtin_amdgcn_mfma_f32_16x16x32_bf16(kf1, qf[1], a, 0, 0, 0);
      const float p0 = fexp2(a[0]);  // masked keys: exact 0
      const float p1 = fexp2(a[1]);
      const float p2 = fexp2(a[2]);
      const float p3 = fexp2(a[3]);
      lp += (p0 + p1) + (p2 + p3);
      const u64 pk = (u64)pkbf(p0, p1) | ((u64)pkbf(p2, p3) << 32);
      const s4v pc = __builtin_bit_cast(s4v, pk);
      if (nt & 1)
        pbx[nt >> 1] = cat8(pbe, pc);
      else
        pbe = pc;
    }
    // O^T += V^T . P^T on K=32 MFMA, V in natural key order
#pragma unroll
    for (int kh = 0; kh < 2; ++kh) {
      const u16* vtc = &vt[cur][kh][0];
#pragma unroll
      for (int dt = 0; dt < 4; ++dt) {
        const int vrow = dt * 16 + ln;
        const int rx = vrow & 7;
        const u16* vb = vtc + vrow * 64;
#pragma unroll
        for (int g2 = 0; g2 < 2; ++g2) {
          const bfv8 av = *(const bfv8*)(vb + (((g2 * 4 + q) ^ rx) * 8));
          ot[dt] = __builtin_amdgcn_mfma_f32_16x16x32_bf16(
              av, pbx[kh * 2 + g2], ot[dt], 0, 0, 0);
        }
      }
    }
  }
  // row-sum: reduce across the 4 quads (same qrow), normalize, store
  lp += __shfl_xor(lp, 16);
  lp += __shfl_xor(lp, 32);
  const float linv = (mb[lq + ln] > -100.0f) ? (1.0f / lp) : 0.0f;
#pragma unroll
  for (int dt = 0; dt < 4; ++dt) {
    const u64 pk = (u64)pkbf(ot[dt][0] * linv, ot[dt][1] * linv) |
                   ((u64)pkbf(ot[dt][2] * linv, ot[dt][3] * linv) << 32);
    *(u64*)(Hd + (size_t)(b * L + lq + ln) * E + h * DK + dt * 16 + q * 4) =
        pk;
  }
}

// ---------- Kernel 3: output projection as GEMM ----------
__global__ __launch_bounds__(256, 2) void k_projg(const u16* __restrict__ WoT,
                                                  const u16* __restrict__ Hd,
                                                  float* __restrict__ out) {
  __shared__ u16 As[64 * 64];   // 8 KB
  __shared__ u16 Bs[128 * 64];  // 16 KB
  const int bm = blockIdx.x, bn = blockIdx.y;
  f4 acc[2][4];
#pragma unroll
  for (int mt = 0; mt < 2; ++mt)
#pragma unroll
    for (int nt = 0; nt < 4; ++nt) acc[mt][nt] = (f4){0.f, 0.f, 0.f, 0.f};
  gemm_tile<64>(WoT, Hd, bm * 64, bn * 128, As, Bs, acc);

  const int tid = threadIdx.x, wid = tid >> 6, lane = tid & 63;
  const int q = lane >> 4, ln = lane & 15;
  const int wr = wid >> 1, wc = wid & 1;
#pragma unroll
  for (int mt = 0; mt < 2; ++mt)
#pragma unroll
    for (int nt = 0; nt < 4; ++nt)
#pragma unroll
      for (int r = 0; r < 4; ++r) {
        const int d = bm * 64 + wr * 32 + mt * 16 + q * 4 + r;
        const int n = bn * 128 + wc * 64 + nt * 16 + ln;
        const int bb = n >> 11, l = n & 2047;
        out[((size_t)(bb * D + d)) * L + l] = acc[mt][nt][r];
      }
}

extern "C" void kernel_launch(void* const* d_in, const int* in_sizes, int n_in,
                              void* d_out, int out_size, void* d_ws,
                              size_t ws_size, hipStream_t stream) {
  const float* x    = (const float*)d_in[0];
  const float* mask = (const float*)d_in[1];
  const float* Wq   = (const float*)d_in[2];
  const float* Wk   = (const float*)d_in[3];
  const float* Wv   = (const float*)d_in[4];
  const float* Wo   = (const float*)d_in[5];
  u16* ws = (u16*)d_ws;
  u16* Qws  = ws;              // 4194304
  u16* Kws  = ws + 4194304;    // 4194304
  u16* Vtws = ws + 8388608;    // 4194304
  u16* WoTw = ws + 12582912;   // 1048576
  u16* Wtws = ws + 13631488;   // 3145728
  u16* xtws = ws + 16777216;   // 4194304 (xt dead after k_qkvg)
  u16* Hdws = ws + 16777216;   // alias of xt

  k_prep<<<2048, 256, 0, stream>>>(x, Wq, Wk, Wv, Wo, xtws, Wtws, WoTw);
  k_qkvg<<<dim3(32, 24), 256, 0, stream>>>(xtws, Wtws, Qws, Kws, Vtws);
  k_attn<<<dim3(16, 16, 2), 512, 0, stream>>>(Qws, Kws, Vtws, mask, Hdws);
  k_projg<<<dim3(16, 32), 256, 0, stream>>>(WoTw, Hdws, (float*)d_out);
}

// Round 2
// 182.271 us; speedup vs baseline: 1.0159x; 1.0043x over previous
//
#include <hip/hip_runtime.h>
#include <hip/hip_bf16.h>

typedef unsigned short u16;
typedef unsigned int u32;
typedef unsigned long long u64;
typedef short s8v __attribute__((ext_vector_type(8)));
typedef __bf16 bfv8 __attribute__((ext_vector_type(8)));
typedef float f4 __attribute__((ext_vector_type(4)));
typedef float f16v __attribute__((ext_vector_type(16)));

static constexpr int B = 2, D = 1024, L = 2048, H = 16, DK = 64, E = 1024;
// fold 1/sqrt(DK) and log2(e) into Q so softmax runs natively in exp2 domain
static constexpr float QSCALE = 0.125f * 1.44269504088896340736f;
static constexpr float SMB = -16.0f;       // fixed softmax bias (|s|<~10)
static constexpr float MASKB = -12000.0f;  // exp2(MASKB+s) == 0.0f exactly

#define DEV __device__ __forceinline__

DEV u16 f2bf(float f) {  // fp32 -> bf16 round-to-nearest-even
  unsigned int u = __float_as_uint(f);
  u += 0x7FFFu + ((u >> 16) & 1u);
  return (u16)(u >> 16);
}
DEV float fexp2(float x) { return __builtin_amdgcn_exp2f(x); }
DEV u32 pkbf(float a, float b) {  // packed fp32x2 -> bf16x2 (v_cvt_pk)
  __hip_bfloat162 h = __float22bfloat162_rn(float2{a, b});
  u32 r;
  __builtin_memcpy(&r, &h, 4);
  return r;
}
// key-permutation for 32x32 QK^T -> PV handoff: LDS kt row k holds physical
// key kperm32(k). C-layout row r (half h) = (r&3)+8*(r>>2)+4*h must equal
// physical key 16*(r>>3)+8*h+(r&7)  =>  swap bits 2 and 3 of the row index.
DEV int kperm32(int k) {
  return (k & ~12) | ((k & 4) << 1) | ((k & 8) >> 1);
}

#define GLD_LDS16(gp, lp)                                                     \
  __builtin_amdgcn_global_load_lds(                                           \
      (const __attribute__((address_space(1))) void*)(gp),                    \
      (__attribute__((address_space(3))) void*)(lp), 16, 0, 0)

// ---------- Kernel 0: fused fp32->bf16 64x64 tile transposes ----------
__global__ __launch_bounds__(256) void k_prep(
    const float* __restrict__ x, const float* __restrict__ Wq,
    const float* __restrict__ Wk, const float* __restrict__ Wv,
    const float* __restrict__ Wo, u16* __restrict__ xt, u16* __restrict__ Wt,
    u16* __restrict__ WoT) {
  __shared__ u16 t[64][67];
  const int tid = threadIdx.x;
  const int g = blockIdx.x;
  const float* src;
  u16* dst;
  int sld, dld;
  if (g < 1024) {
    const int b = g >> 9, dt = (g >> 5) & 15, lt = g & 31;
    src = x + ((size_t)b * D + dt * 64) * L + lt * 64;
    sld = L;
    dst = xt + ((size_t)b * L + lt * 64) * D + dt * 64;
    dld = D;
  } else if (g < 1792) {
    const int u = g - 1024;
    const int w = u >> 8, h = (u >> 4) & 15, dt = u & 15;
    const float* Ws = (w == 0) ? Wq : ((w == 1) ? Wk : Wv);
    src = Ws + ((size_t)h * D + dt * 64) * DK;
    sld = DK;
    dst = Wt + ((size_t)(w * H + h) * DK) * D + dt * 64;
    dld = D;
  } else {
    const int v = g - 1792;
    const int et = v >> 4, dt = v & 15;
    src = Wo + ((size_t)et * 64) * D + dt * 64;
    sld = D;
    dst = WoT + ((size_t)dt * 64) * E + et * 64;
    dld = E;
  }
  const int r = tid >> 2, c16 = (tid & 3) * 16;
#pragma unroll
  for (int j = 0; j < 16; j += 4) {
    const f4 v4 = *(const f4*)(src + (size_t)r * sld + c16 + j);
    t[r][c16 + j]     = f2bf(v4[0]);
    t[r][c16 + j + 1] = f2bf(v4[1]);
    t[r][c16 + j + 2] = f2bf(v4[2]);
    t[r][c16 + j + 3] = f2bf(v4[3]);
  }
  __syncthreads();
  s8v o0, o1;
#pragma unroll
  for (int i = 0; i < 8; ++i) {
    o0[i] = (short)t[c16 + i][r];
    o1[i] = (short)t[c16 + 8 + i][r];
  }
  *(s8v*)(dst + (size_t)r * dld + c16)     = o0;
  *(s8v*)(dst + (size_t)r * dld + c16 + 8) = o1;
}

// ---------- shared GEMM tile core: BK=64, single-buffer, 1 barrier-pair ----
// LDS tiles [rows][64] u16 (128B rows), swizzle phys_chunk = logical^(row&7).
// 16 K-iterations (vs 32 at BK=32): half the barrier/drain tax, same bytes.
template <int AR>
DEV void gemm_tile(const u16* __restrict__ A, const u16* __restrict__ Bt,
                   int arow0, int brow0, u16* As, u16* Bs,
                   f4 (&acc)[AR / 32][4]) {
  const int tid = threadIdx.x;
  const int wid = tid >> 6, lane = tid & 63;
  const int q = lane >> 4, ln = lane & 15;
  const int wr = wid >> 1, wc = wid & 1;
  const int lrow = lane >> 3;        // 0..7 (dest row & 7)
  const int lc = (lane & 7) ^ lrow;  // logical chunk for swizzled dest
  const int f0 = (q ^ (ln & 7)) * 8;        // frag phys chunk, k-step 0
  const int f1 = ((q + 4) ^ (ln & 7)) * 8;  // k-step 1
  constexpr int MT = AR / 32;

  for (int k0 = 0; k0 < 1024; k0 += 64) {
    __syncthreads();
#pragma unroll
    for (int j = 0; j < AR / 32; ++j) {  // A: 8 rows per instr
      const int rb = wid * (AR / 4) + j * 8;
      GLD_LDS16(A + (size_t)(arow0 + rb + lrow) * 1024 + k0 + lc * 8,
                As + rb * 64);
    }
#pragma unroll
    for (int j = 0; j < 4; ++j) {  // B: 128 rows
      const int rb = wid * 32 + j * 8;
      GLD_LDS16(Bt + (size_t)(brow0 + rb + lrow) * 1024 + k0 + lc * 8,
                Bs + rb * 64);
    }
    __syncthreads();
#pragma unroll
    for (int ks = 0; ks < 2; ++ks) {
      const int fc = ks ? f1 : f0;
      bfv8 af[MT], bf[4];
#pragma unroll
      for (int mt = 0; mt < MT; ++mt)
        af[mt] = *(const bfv8*)(As + (wr * (AR / 2) + mt * 16 + ln) * 64 + fc);
#pragma unroll
      for (int nt = 0; nt < 4; ++nt)
        bf[nt] = *(const bfv8*)(Bs + (wc * 64 + nt * 16 + ln) * 64 + fc);
#pragma unroll
      for (int mt = 0; mt < MT; ++mt)
#pragma unroll
        for (int nt = 0; nt < 4; ++nt)
          acc[mt][nt] = __builtin_amdgcn_mfma_f32_16x16x32_bf16(
              af[mt], bf[nt], acc[mt][nt], 0, 0, 0);
    }
  }
}

// ---------- Kernel 1: QKV projection as one GEMM ----------
__global__ __launch_bounds__(256, 3) void k_qkvg(
    const u16* __restrict__ xt, const u16* __restrict__ Wt,
    u16* __restrict__ Q, u16* __restrict__ K, u16* __restrict__ Vt) {
  __shared__ u16 As[128 * 64];  // 16 KB
  __shared__ u16 Bs[128 * 64];  // 16 KB  (32 KB total: 3 blocks/CU ok)
  const int bm = blockIdx.x, bn = blockIdx.y;
  f4 acc[4][4];
#pragma unroll
  for (int mt = 0; mt < 4; ++mt)
#pragma unroll
    for (int nt = 0; nt < 4; ++nt) acc[mt][nt] = (f4){0.f, 0.f, 0.f, 0.f};
  gemm_tile<128>(xt, Wt, bm * 128, bn * 128, As, Bs, acc);

  const int tid = threadIdx.x, wid = tid >> 6, lane = tid & 63;
  const int q = lane >> 4, ln = lane & 15;
  const int wr = wid >> 1, wc = wid & 1;
  const int h2 = bn * 2 + wc;  // 0..47
  const int wsel = h2 >> 4, h = h2 & 15;
  const int b = bm >> 4;
  const int lbase = (bm & 15) * 128 + wr * 64;
  if (wsel == 0) {
    u16* dst = Q + (size_t)(b * H + h) * L * DK;
#pragma unroll
    for (int mt = 0; mt < 4; ++mt)
#pragma unroll
      for (int nt = 0; nt < 4; ++nt)
#pragma unroll
        for (int r = 0; r < 4; ++r)
          dst[(size_t)(lbase + mt * 16 + q * 4 + r) * DK + nt * 16 + ln] =
              f2bf(acc[mt][nt][r] * QSCALE);
  } else if (wsel == 1) {
    u16* dst = K + (size_t)(b * H + h) * L * DK;
#pragma unroll
    for (int mt = 0; mt < 4; ++mt)
#pragma unroll
      for (int nt = 0; nt < 4; ++nt)
#pragma unroll
        for (int r = 0; r < 4; ++r)
          dst[(size_t)(lbase + mt * 16 + q * 4 + r) * DK + nt * 16 + ln] =
              f2bf(acc[mt][nt][r]);
  } else {
    // V: plain transpose Vt[dk][l], 4 consecutive l per lane -> 8B stores
    u16* dst = Vt + (size_t)(b * H + h) * DK * L;
#pragma unroll
    for (int mt = 0; mt < 4; ++mt)
#pragma unroll
      for (int nt = 0; nt < 4; ++nt) {
        const u64 pk = (u64)pkbf(acc[mt][nt][0], acc[mt][nt][1]) |
                       ((u64)pkbf(acc[mt][nt][2], acc[mt][nt][3]) << 32);
        *(u64*)(dst + (size_t)(nt * 16 + ln) * L + lbase + mt * 16 + q * 4) =
            pk;
      }
  }
}

// ---------- Kernel 2: flash attention, 128-key tiles ----------
// R13: 32x32x16 MFMA for both QK^T and PV: 2x FLOPs per LDS-read byte vs
// 16x16x32 (the R12 LDS-read wall). 4 waves x 32 q-rows, 2 blocks/CU.
__global__ __launch_bounds__(256, 2) void k_attn(
    const u16* __restrict__ Q, const u16* __restrict__ K,
    const u16* __restrict__ Vt, const float* __restrict__ mask,
    u16* __restrict__ Hd) {
  __shared__ u16 kt[2][128 * 64];    // [keyrow(permuted)][dk], chunk-swizzled
  __shared__ u16 vt[2][2][64 * 64];  // [half][dk][key(natural)], same swizzle
  __shared__ __align__(16) float mb[L];  // per-key bias: SMB or MASKB
  const int h = blockIdx.x, lt = blockIdx.y, b = blockIdx.z;
  const int tid = threadIdx.x;
  const int w = tid >> 6, lane = tid & 63;
  const int l5 = lane & 31, hi = lane >> 5;
  for (int i = tid; i < L; i += 256)
    mb[i] = (mask[(size_t)b * L + i] != 0.0f) ? SMB : MASKB;

  const int bh = b * H + h;
  const u16* Qp = Q + (size_t)bh * L * DK;
  const u16* Kp = K + (size_t)bh * L * DK;
  const u16* Vp = Vt + (size_t)bh * DK * L;
  const int lq = lt * 128 + w * 32;  // wave covers 32 q-rows

  // Q B-frags: B[k=hi*8+j][n=l5] per 16-dk step
  bfv8 qf[4];
#pragma unroll
  for (int st = 0; st < 4; ++st)
    qf[st] = *(const bfv8*)(Qp + (size_t)(lq + l5) * DK + st * 16 + hi * 8);

  const int lrow = lane >> 3;        // 0..7 (== dest row & 7)
  const int lc = (lane & 7) ^ lrow;  // logical chunk for swizzled dest
  const int x7 = lane & 7;
  int kpr[4];  // permuted K source rows (loop-invariant)
#pragma unroll
  for (int j = 0; j < 4; ++j) kpr[j] = kperm32(w * 32 + j * 8 + lrow);

  auto stage = [&](int m0, int bufi) {
    // kt: 128 rows, 4 waves x 32 rows, bit2<->bit3-permuted key order
#pragma unroll
    for (int j = 0; j < 4; ++j) {
      GLD_LDS16(Kp + (size_t)(m0 + kpr[j]) * DK + lc * 8,
                &kt[bufi][(w * 32 + j * 8) * 64]);
    }
    // vt: per half 64 dk-rows, 4 waves x 16 rows, natural key order
#pragma unroll
    for (int kh = 0; kh < 2; ++kh)
#pragma unroll
      for (int j = 0; j < 2; ++j) {
        const int fr = w * 16 + j * 8 + lrow;
        GLD_LDS16(Vp + (size_t)fr * L + m0 + kh * 64 + lc * 8,
                  &vt[bufi][kh][(w * 16 + j * 8) * 64]);
      }
  };

  f16v ot[2];  // O^T[dk=dt*32+(reg&3)+8*(reg>>2)+4*hi][qrow=l5]
#pragma unroll
  for (int dt = 0; dt < 2; ++dt)
#pragma unroll
    for (int i = 0; i < 16; ++i) ot[dt][i] = 0.f;
  float lp = 0.f;  // row-sum over this hi-half's keys

  stage(0, 0);
  for (int it = 0; it < L / 128; ++it) {
    const int m0 = it * 128;
    __syncthreads();  // buf(it&1) landed; mb ready; prev buf reads done
    if (it + 1 < L / 128) stage(m0 + 128, (it + 1) & 1);
    const int cur = it & 1;
    const u16* ktc = &kt[cur][0];
#pragma unroll
    for (int s = 0; s < 4; ++s) {  // 32-key strips
      // C init = mask bias at the physical key of each output reg quad
      union {
        f4 q[4];
        f16v v;
      } ai;
#pragma unroll
      for (int rq = 0; rq < 4; ++rq)
        ai.q[rq] = *(const f4*)(mb + m0 + s * 32 + (rq >> 1) * 16 + hi * 8 +
                                (rq & 1) * 4);
      f16v a = ai.v;
#pragma unroll
      for (int st = 0; st < 4; ++st) {  // K=16 dk-steps
        const bfv8 kf = *(const bfv8*)(ktc + (s * 32 + l5) * 64 +
                                       ((st * 2 + hi) ^ x7) * 8);
        a = __builtin_amdgcn_mfma_f32_32x32x16_bf16(kf, qf[st], a, 0, 0, 0);
      }
      float p[16];
#pragma unroll
      for (int i = 0; i < 16; ++i) p[i] = fexp2(a[i]);  // masked: exact 0
      const float t0 = (p[0] + p[1]) + (p[2] + p[3]);
      const float t1 = (p[4] + p[5]) + (p[6] + p[7]);
      const float t2 = (p[8] + p[9]) + (p[10] + p[11]);
      const float t3 = (p[12] + p[13]) + (p[14] + p[15]);
      lp += (t0 + t1) + (t2 + t3);
      // regs g*8..g*8+7 are exactly PV B-frag for key group g (kperm32)
      union {
        u32 w4[4];
        bfv8 v;
      } pb[2];
#pragma unroll
      for (int g = 0; g < 2; ++g)
#pragma unroll
        for (int k2 = 0; k2 < 4; ++k2)
          pb[g].w4[k2] = pkbf(p[g * 8 + k2 * 2], p[g * 8 + k2 * 2 + 1]);
      // O^T += V^T . P^T on 32x32x16, V in natural key order
#pragma unroll
      for (int g = 0; g < 2; ++g) {
        const int kg = s * 2 + g;  // 16-key group 0..7
        const u16* vtc = &vt[cur][kg >> 2][0];
        const int cb = (((kg & 3) * 2 + hi) ^ x7) * 8;
#pragma unroll
        for (int dt = 0; dt < 2; ++dt) {
          const bfv8 av = *(const bfv8*)(vtc + (dt * 32 + l5) * 64 + cb);
          ot[dt] = __builtin_amdgcn_mfma_f32_32x32x16_bf16(av, pb[g].v,
                                                           ot[dt], 0, 0, 0);
        }
      }
    }
  }
  // row-sum: combine the two hi halves (same qrow), normalize, store
  lp += __shfl_xor(lp, 32);
  const float linv = (mb[lq + l5] > -100.0f) ? (1.0f / lp) : 0.0f;
#pragma unroll
  for (int dt = 0; dt < 2; ++dt)
#pragma unroll
    for (int rq = 0; rq < 4; ++rq) {
      const u64 pk =
          (u64)pkbf(ot[dt][rq * 4 + 0] * linv, ot[dt][rq * 4 + 1] * linv) |
          ((u64)pkbf(ot[dt][rq * 4 + 2] * linv, ot[dt][rq * 4 + 3] * linv)
           << 32);
      *(u64*)(Hd + (size_t)(b * L + lq + l5) * E + h * DK + dt * 32 + rq * 8 +
              hi * 4) = pk;
    }
}

// ---------- Kernel 3: output projection as GEMM ----------
__global__ __launch_bounds__(256, 2) void k_projg(const u16* __restrict__ WoT,
                                                  const u16* __restrict__ Hd,
                                                  float* __restrict__ out) {
  __shared__ u16 As[64 * 64];   // 8 KB
  __shared__ u16 Bs[128 * 64];  // 16 KB
  const int bm = blockIdx.x, bn = blockIdx.y;
  f4 acc[2][4];
#pragma unroll
  for (int mt = 0; mt < 2; ++mt)
#pragma unroll
    for (int nt = 0; nt < 4; ++nt) acc[mt][nt] = (f4){0.f, 0.f, 0.f, 0.f};
  gemm_tile<64>(WoT, Hd, bm * 64, bn * 128, As, Bs, acc);

  const int tid = threadIdx.x, wid = tid >> 6, lane = tid & 63;
  const int q = lane >> 4, ln = lane & 15;
  const int wr = wid >> 1, wc = wid & 1;
#pragma unroll
  for (int mt = 0; mt < 2; ++mt)
#pragma unroll
    for (int nt = 0; nt < 4; ++nt)
#pragma unroll
      for (int r = 0; r < 4; ++r) {
        const int d = bm * 64 + wr * 32 + mt * 16 + q * 4 + r;
        const int n = bn * 128 + wc * 64 + nt * 16 + ln;
        const int bb = n >> 11, l = n & 2047;
        out[((size_t)(bb * D + d)) * L + l] = acc[mt][nt][r];
      }
}

extern "C" void kernel_launch(void* const* d_in, const int* in_sizes, int n_in,
                              void* d_out, int out_size, void* d_ws,
                              size_t ws_size, hipStream_t stream) {
  const float* x    = (const float*)d_in[0];
  const float* mask = (const float*)d_in[1];
  const float* Wq   = (const float*)d_in[2];
  const float* Wk   = (const float*)d_in[3];
  const float* Wv   = (const float*)d_in[4];
  const float* Wo   = (const float*)d_in[5];
  u16* ws = (u16*)d_ws;
  u16* Qws  = ws;              // 4194304
  u16* Kws  = ws + 4194304;    // 4194304
  u16* Vtws = ws + 8388608;    // 4194304
  u16* WoTw = ws + 12582912;   // 1048576
  u16* Wtws = ws + 13631488;   // 3145728
  u16* xtws = ws + 16777216;   // 4194304 (xt dead after k_qkvg)
  u16* Hdws = ws + 16777216;   // alias of xt

  k_prep<<<2048, 256, 0, stream>>>(x, Wq, Wk, Wv, Wo, xtws, Wtws, WoTw);
  k_qkvg<<<dim3(32, 24), 256, 0, stream>>>(xtws, Wtws, Qws, Kws, Vtws);
  k_attn<<<dim3(16, 16, 2), 256, 0, stream>>>(Qws, Kws, Vtws, mask, Hdws);
  k_projg<<<dim3(16, 32), 256, 0, stream>>>(WoTw, Hdws, (float*)d_out);
}

// Round 3
// 177.937 us; speedup vs baseline: 1.0407x; 1.0244x over previous
//
#include <hip/hip_runtime.h>
#include <hip/hip_bf16.h>

typedef unsigned short u16;
typedef unsigned int u32;
typedef unsigned long long u64;
typedef short s8v __attribute__((ext_vector_type(8)));
typedef __bf16 bfv8 __attribute__((ext_vector_type(8)));
typedef float f4 __attribute__((ext_vector_type(4)));
typedef float f16v __attribute__((ext_vector_type(16)));

static constexpr int B = 2, D = 1024, L = 2048, H = 16, DK = 64, E = 1024;
// fold 1/sqrt(DK) and log2(e) into Q so softmax runs natively in exp2 domain
static constexpr float QSCALE = 0.125f * 1.44269504088896340736f;
static constexpr float SMB = -16.0f;       // fixed softmax bias (|s|<~10)
static constexpr float MASKB = -12000.0f;  // exp2(MASKB+s) == 0.0f exactly

#define DEV __device__ __forceinline__

DEV u16 f2bf(float f) {  // fp32 -> bf16 round-to-nearest-even
  unsigned int u = __float_as_uint(f);
  u += 0x7FFFu + ((u >> 16) & 1u);
  return (u16)(u >> 16);
}
DEV float fexp2(float x) { return __builtin_amdgcn_exp2f(x); }
DEV u32 pkbf(float a, float b) {  // packed fp32x2 -> bf16x2 (v_cvt_pk)
  __hip_bfloat162 h = __float22bfloat162_rn(float2{a, b});
  u32 r;
  __builtin_memcpy(&r, &h, 4);
  return r;
}
// key-permutation for 32x32 QK^T -> PV handoff: LDS kt row k holds physical
// key kperm32(k). C-layout row r (half h) = (r&3)+8*(r>>2)+4*h must equal
// physical key 16*(r>>3)+8*h+(r&7)  =>  swap bits 2 and 3 of the row index.
DEV int kperm32(int k) {
  return (k & ~12) | ((k & 4) << 1) | ((k & 8) >> 1);
}

#define GLD_LDS16(gp, lp)                                                     \
  __builtin_amdgcn_global_load_lds(                                           \
      (const __attribute__((address_space(1))) void*)(gp),                    \
      (__attribute__((address_space(3))) void*)(lp), 16, 0, 0)

// ---------- Kernel 0: fused fp32->bf16 64x64 tile transposes ----------
__global__ __launch_bounds__(256) void k_prep(
    const float* __restrict__ x, const float* __restrict__ Wq,
    const float* __restrict__ Wk, const float* __restrict__ Wv,
    const float* __restrict__ Wo, u16* __restrict__ xt, u16* __restrict__ Wt,
    u16* __restrict__ WoT) {
  __shared__ u16 t[64][67];
  const int tid = threadIdx.x;
  const int g = blockIdx.x;
  const float* src;
  u16* dst;
  int sld, dld;
  if (g < 1024) {
    const int b = g >> 9, dt = (g >> 5) & 15, lt = g & 31;
    src = x + ((size_t)b * D + dt * 64) * L + lt * 64;
    sld = L;
    dst = xt + ((size_t)b * L + lt * 64) * D + dt * 64;
    dld = D;
  } else if (g < 1792) {
    const int u = g - 1024;
    const int w = u >> 8, h = (u >> 4) & 15, dt = u & 15;
    const float* Ws = (w == 0) ? Wq : ((w == 1) ? Wk : Wv);
    src = Ws + ((size_t)h * D + dt * 64) * DK;
    sld = DK;
    dst = Wt + ((size_t)(w * H + h) * DK) * D + dt * 64;
    dld = D;
  } else {
    const int v = g - 1792;
    const int et = v >> 4, dt = v & 15;
    src = Wo + ((size_t)et * 64) * D + dt * 64;
    sld = D;
    dst = WoT + ((size_t)dt * 64) * E + et * 64;
    dld = E;
  }
  const int r = tid >> 2, c16 = (tid & 3) * 16;
#pragma unroll
  for (int j = 0; j < 16; j += 4) {
    const f4 v4 = *(const f4*)(src + (size_t)r * sld + c16 + j);
    t[r][c16 + j]     = f2bf(v4[0]);
    t[r][c16 + j + 1] = f2bf(v4[1]);
    t[r][c16 + j + 2] = f2bf(v4[2]);
    t[r][c16 + j + 3] = f2bf(v4[3]);
  }
  __syncthreads();
  s8v o0, o1;
#pragma unroll
  for (int i = 0; i < 8; ++i) {
    o0[i] = (short)t[c16 + i][r];
    o1[i] = (short)t[c16 + 8 + i][r];
  }
  *(s8v*)(dst + (size_t)r * dld + c16)     = o0;
  *(s8v*)(dst + (size_t)r * dld + c16 + 8) = o1;
}

// ---------- shared GEMM tile core: BK=64, single-buffer, 1 barrier-pair ----
// LDS tiles [rows][64] u16 (128B rows), swizzle phys_chunk = logical^(row&7).
// 16 K-iterations (vs 32 at BK=32): half the barrier/drain tax, same bytes.
template <int AR>
DEV void gemm_tile(const u16* __restrict__ A, const u16* __restrict__ Bt,
                   int arow0, int brow0, u16* As, u16* Bs,
                   f4 (&acc)[AR / 32][4]) {
  const int tid = threadIdx.x;
  const int wid = tid >> 6, lane = tid & 63;
  const int q = lane >> 4, ln = lane & 15;
  const int wr = wid >> 1, wc = wid & 1;
  const int lrow = lane >> 3;        // 0..7 (dest row & 7)
  const int lc = (lane & 7) ^ lrow;  // logical chunk for swizzled dest
  const int f0 = (q ^ (ln & 7)) * 8;        // frag phys chunk, k-step 0
  const int f1 = ((q + 4) ^ (ln & 7)) * 8;  // k-step 1
  constexpr int MT = AR / 32;

  for (int k0 = 0; k0 < 1024; k0 += 64) {
    __syncthreads();
#pragma unroll
    for (int j = 0; j < AR / 32; ++j) {  // A: 8 rows per instr
      const int rb = wid * (AR / 4) + j * 8;
      GLD_LDS16(A + (size_t)(arow0 + rb + lrow) * 1024 + k0 + lc * 8,
                As + rb * 64);
    }
#pragma unroll
    for (int j = 0; j < 4; ++j) {  // B: 128 rows
      const int rb = wid * 32 + j * 8;
      GLD_LDS16(Bt + (size_t)(brow0 + rb + lrow) * 1024 + k0 + lc * 8,
                Bs + rb * 64);
    }
    __syncthreads();
#pragma unroll
    for (int ks = 0; ks < 2; ++ks) {
      const int fc = ks ? f1 : f0;
      bfv8 af[MT], bf[4];
#pragma unroll
      for (int mt = 0; mt < MT; ++mt)
        af[mt] = *(const bfv8*)(As + (wr * (AR / 2) + mt * 16 + ln) * 64 + fc);
#pragma unroll
      for (int nt = 0; nt < 4; ++nt)
        bf[nt] = *(const bfv8*)(Bs + (wc * 64 + nt * 16 + ln) * 64 + fc);
#pragma unroll
      for (int mt = 0; mt < MT; ++mt)
#pragma unroll
        for (int nt = 0; nt < 4; ++nt)
          acc[mt][nt] = __builtin_amdgcn_mfma_f32_16x16x32_bf16(
              af[mt], bf[nt], acc[mt][nt], 0, 0, 0);
    }
  }
}

// ---------- Kernel 1: QKV projection as one GEMM ----------
__global__ __launch_bounds__(256, 3) void k_qkvg(
    const u16* __restrict__ xt, const u16* __restrict__ Wt,
    u16* __restrict__ Q, u16* __restrict__ K, u16* __restrict__ Vt) {
  __shared__ u16 As[128 * 64];  // 16 KB
  __shared__ u16 Bs[128 * 64];  // 16 KB  (32 KB total: 3 blocks/CU ok)
  const int bm = blockIdx.x, bn = blockIdx.y;
  f4 acc[4][4];
#pragma unroll
  for (int mt = 0; mt < 4; ++mt)
#pragma unroll
    for (int nt = 0; nt < 4; ++nt) acc[mt][nt] = (f4){0.f, 0.f, 0.f, 0.f};
  gemm_tile<128>(xt, Wt, bm * 128, bn * 128, As, Bs, acc);

  const int tid = threadIdx.x, wid = tid >> 6, lane = tid & 63;
  const int q = lane >> 4, ln = lane & 15;
  const int wr = wid >> 1, wc = wid & 1;
  const int h2 = bn * 2 + wc;  // 0..47
  const int wsel = h2 >> 4, h = h2 & 15;
  const int b = bm >> 4;
  const int lbase = (bm & 15) * 128 + wr * 64;
  if (wsel == 0) {
    u16* dst = Q + (size_t)(b * H + h) * L * DK;
#pragma unroll
    for (int mt = 0; mt < 4; ++mt)
#pragma unroll
      for (int nt = 0; nt < 4; ++nt)
#pragma unroll
        for (int r = 0; r < 4; ++r)
          dst[(size_t)(lbase + mt * 16 + q * 4 + r) * DK + nt * 16 + ln] =
              f2bf(acc[mt][nt][r] * QSCALE);
  } else if (wsel == 1) {
    u16* dst = K + (size_t)(b * H + h) * L * DK;
#pragma unroll
    for (int mt = 0; mt < 4; ++mt)
#pragma unroll
      for (int nt = 0; nt < 4; ++nt)
#pragma unroll
        for (int r = 0; r < 4; ++r)
          dst[(size_t)(lbase + mt * 16 + q * 4 + r) * DK + nt * 16 + ln] =
              f2bf(acc[mt][nt][r]);
  } else {
    // V: plain transpose Vt[dk][l], 4 consecutive l per lane -> 8B stores
    u16* dst = Vt + (size_t)(b * H + h) * DK * L;
#pragma unroll
    for (int mt = 0; mt < 4; ++mt)
#pragma unroll
      for (int nt = 0; nt < 4; ++nt) {
        const u64 pk = (u64)pkbf(acc[mt][nt][0], acc[mt][nt][1]) |
                       ((u64)pkbf(acc[mt][nt][2], acc[mt][nt][3]) << 32);
        *(u64*)(dst + (size_t)(nt * 16 + ln) * L + lbase + mt * 16 + q * 4) =
            pk;
      }
  }
}

// ---------- Kernel 2: flash attention, 128-key tiles ----------
// R14: 8 waves = 4 wq (32 q-rows each) x 2 wk (64-key halves). 32x32 MFMA
// pipeline (R13) at 16 waves/CU (R12's occupancy). Per-wave serial chain
// halves; cross-wk O/lp reduction through LDS scratch at the end.
__global__ __launch_bounds__(512, 4) void k_attn(
    const u16* __restrict__ Q, const u16* __restrict__ K,
    const u16* __restrict__ Vt, const float* __restrict__ mask,
    u16* __restrict__ Hd) {
  __shared__ u16 kt[2][128 * 64];    // [keyrow(permuted)][dk], chunk-swizzled
  __shared__ u16 vt[2][2][64 * 64];  // [half][dk][key(natural)], same swizzle
  __shared__ __align__(16) float mb[L];  // per-key bias: SMB or MASKB
  const int h = blockIdx.x, lt = blockIdx.y, b = blockIdx.z;
  const int tid = threadIdx.x;
  const int w = tid >> 6, lane = tid & 63;
  const int l5 = lane & 31, hi = lane >> 5;
  const int wq = w >> 1, wk = w & 1;
  for (int i = tid; i < L; i += 512)
    mb[i] = (mask[(size_t)b * L + i] != 0.0f) ? SMB : MASKB;

  const int bh = b * H + h;
  const u16* Qp = Q + (size_t)bh * L * DK;
  const u16* Kp = K + (size_t)bh * L * DK;
  const u16* Vp = Vt + (size_t)bh * DK * L;
  const int lq = lt * 128 + wq * 32;  // wave covers 32 q-rows

  // Q B-frags: B[k=hi*8+j][n=l5] per 16-dk step
  bfv8 qf[4];
#pragma unroll
  for (int st = 0; st < 4; ++st)
    qf[st] = *(const bfv8*)(Qp + (size_t)(lq + l5) * DK + st * 16 + hi * 8);

  const int lrow = lane >> 3;        // 0..7 (== dest row & 7)
  const int lc = (lane & 7) ^ lrow;  // logical chunk for swizzled dest
  const int x7 = lane & 7;
  int kpr[2];  // permuted K source rows (loop-invariant)
#pragma unroll
  for (int j = 0; j < 2; ++j) kpr[j] = kperm32(w * 16 + j * 8 + lrow);

  auto stage = [&](int m0, int bufi) {
    // kt: 128 rows, 8 waves x 16 rows, bit2<->bit3-permuted key order
#pragma unroll
    for (int j = 0; j < 2; ++j) {
      GLD_LDS16(Kp + (size_t)(m0 + kpr[j]) * DK + lc * 8,
                &kt[bufi][(w * 16 + j * 8) * 64]);
    }
    // vt: 2 halves x 64 dk-rows; wave w -> half w>>2, rows (w&3)*16..+15
    const int kh = w >> 2, wv = w & 3;
#pragma unroll
    for (int j = 0; j < 2; ++j) {
      const int fr = wv * 16 + j * 8 + lrow;
      GLD_LDS16(Vp + (size_t)fr * L + m0 + kh * 64 + lc * 8,
                &vt[bufi][kh][(wv * 16 + j * 8) * 64]);
    }
  };

  union {
    f16v v;
    f4 q[4];
  } ot[2];  // O^T[dk=dt*32+(reg&3)+8*(reg>>2)+4*hi][qrow=l5], this wk's keys
#pragma unroll
  for (int dt = 0; dt < 2; ++dt)
#pragma unroll
    for (int i = 0; i < 16; ++i) ot[dt].v[i] = 0.f;
  float lp = 0.f;  // row-sum over this (wk, hi)'s keys

  stage(0, 0);
  for (int it = 0; it < L / 128; ++it) {
    const int m0 = it * 128;
    __syncthreads();  // buf(it&1) landed; mb ready; prev buf reads done
    if (it + 1 < L / 128) stage(m0 + 128, (it + 1) & 1);
    const int cur = it & 1;
    const u16* ktc = &kt[cur][0];
    const u16* vtc = &vt[cur][wk][0];  // this wk's 16-key groups live here
#pragma unroll
    for (int s2 = 0; s2 < 2; ++s2) {  // this wave's two 32-key strips
      const int s = wk * 2 + s2;
      // C init = mask bias at the physical key of each output reg quad
      union {
        f4 q[4];
        f16v v;
      } ai;
#pragma unroll
      for (int rq = 0; rq < 4; ++rq)
        ai.q[rq] = *(const f4*)(mb + m0 + s * 32 + (rq >> 1) * 16 + hi * 8 +
                                (rq & 1) * 4);
      f16v a = ai.v;
      __builtin_amdgcn_s_setprio(1);
#pragma unroll
      for (int st = 0; st < 4; ++st) {  // K=16 dk-steps
        const bfv8 kf = *(const bfv8*)(ktc + (s * 32 + l5) * 64 +
                                       ((st * 2 + hi) ^ x7) * 8);
        a = __builtin_amdgcn_mfma_f32_32x32x16_bf16(kf, qf[st], a, 0, 0, 0);
      }
      __builtin_amdgcn_s_setprio(0);
      float p[16];
#pragma unroll
      for (int i = 0; i < 16; ++i) p[i] = fexp2(a[i]);  // masked: exact 0
      const float t0 = (p[0] + p[1]) + (p[2] + p[3]);
      const float t1 = (p[4] + p[5]) + (p[6] + p[7]);
      const float t2 = (p[8] + p[9]) + (p[10] + p[11]);
      const float t3 = (p[12] + p[13]) + (p[14] + p[15]);
      lp += (t0 + t1) + (t2 + t3);
      // regs g*8..g*8+7 are exactly PV B-frag for key group g (kperm32)
      union {
        u32 w4[4];
        bfv8 v;
      } pb[2];
#pragma unroll
      for (int g = 0; g < 2; ++g)
#pragma unroll
        for (int k2 = 0; k2 < 4; ++k2)
          pb[g].w4[k2] = pkbf(p[g * 8 + k2 * 2], p[g * 8 + k2 * 2 + 1]);
      // O^T += V^T . P^T on 32x32x16, V in natural key order
      __builtin_amdgcn_s_setprio(1);
#pragma unroll
      for (int g = 0; g < 2; ++g) {
        const int kg = s * 2 + g;  // 16-key group; kg>>2 == wk
        const int cb = (((kg & 3) * 2 + hi) ^ x7) * 8;
#pragma unroll
        for (int dt = 0; dt < 2; ++dt) {
          const bfv8 av = *(const bfv8*)(vtc + (dt * 32 + l5) * 64 + cb);
          ot[dt].v = __builtin_amdgcn_mfma_f32_32x32x16_bf16(
              av, pb[g].v, ot[dt].v, 0, 0, 0);
        }
      }
      __builtin_amdgcn_s_setprio(0);
    }
  }
  // combine hi halves (same qrow) within the wave
  lp += __shfl_xor(lp, 32);
  // cross-wk reduction through LDS scratch (kt/vt dead after last iter)
  __syncthreads();
  float* sOt = (float*)&kt[0][0];     // 32 KB: [ (wq*2+dt)*4+rq ][lane] f4
  float* sLp = (float*)&vt[0][0][0];  // 1 KB:  [wq][lane]
  if (wk) {
#pragma unroll
    for (int dt = 0; dt < 2; ++dt)
#pragma unroll
      for (int rq = 0; rq < 4; ++rq)
        *(f4*)(sOt + ((((wq * 2 + dt) * 4 + rq) * 64) + lane) * 4) =
            ot[dt].q[rq];
    sLp[wq * 64 + lane] = lp;
  }
  __syncthreads();
  if (!wk) {
#pragma unroll
    for (int dt = 0; dt < 2; ++dt)
#pragma unroll
      for (int rq = 0; rq < 4; ++rq)
        ot[dt].q[rq] +=
            *(const f4*)(sOt + ((((wq * 2 + dt) * 4 + rq) * 64) + lane) * 4);
    lp += sLp[wq * 64 + lane];
    const float linv = (mb[lq + l5] > -100.0f) ? (1.0f / lp) : 0.0f;
#pragma unroll
    for (int dt = 0; dt < 2; ++dt)
#pragma unroll
      for (int rq = 0; rq < 4; ++rq) {
        const u64 pk = (u64)pkbf(ot[dt].v[rq * 4 + 0] * linv,
                                 ot[dt].v[rq * 4 + 1] * linv) |
                       ((u64)pkbf(ot[dt].v[rq * 4 + 2] * linv,
                                  ot[dt].v[rq * 4 + 3] * linv)
                        << 32);
        *(u64*)(Hd + (size_t)(b * L + lq + l5) * E + h * DK + dt * 32 +
                rq * 8 + hi * 4) = pk;
      }
  }
}

// ---------- Kernel 3: output projection as GEMM ----------
__global__ __launch_bounds__(256, 2) void k_projg(const u16* __restrict__ WoT,
                                                  const u16* __restrict__ Hd,
                                                  float* __restrict__ out) {
  __shared__ u16 As[64 * 64];   // 8 KB
  __shared__ u16 Bs[128 * 64];  // 16 KB
  const int bm = blockIdx.x, bn = blockIdx.y;
  f4 acc[2][4];
#pragma unroll
  for (int mt = 0; mt < 2; ++mt)
#pragma unroll
    for (int nt = 0; nt < 4; ++nt) acc[mt][nt] = (f4){0.f, 0.f, 0.f, 0.f};
  gemm_tile<64>(WoT, Hd, bm * 64, bn * 128, As, Bs, acc);

  const int tid = threadIdx.x, wid = tid >> 6, lane = tid & 63;
  const int q = lane >> 4, ln = lane & 15;
  const int wr = wid >> 1, wc = wid & 1;
#pragma unroll
  for (int mt = 0; mt < 2; ++mt)
#pragma unroll
    for (int nt = 0; nt < 4; ++nt)
#pragma unroll
      for (int r = 0; r < 4; ++r) {
        const int d = bm * 64 + wr * 32 + mt * 16 + q * 4 + r;
        const int n = bn * 128 + wc * 64 + nt * 16 + ln;
        const int bb = n >> 11, l = n & 2047;
        out[((size_t)(bb * D + d)) * L + l] = acc[mt][nt][r];
      }
}

extern "C" void kernel_launch(void* const* d_in, const int* in_sizes, int n_in,
                              void* d_out, int out_size, void* d_ws,
                              size_t ws_size, hipStream_t stream) {
  const float* x    = (const float*)d_in[0];
  const float* mask = (const float*)d_in[1];
  const float* Wq   = (const float*)d_in[2];
  const float* Wk   = (const float*)d_in[3];
  const float* Wv   = (const float*)d_in[4];
  const float* Wo   = (const float*)d_in[5];
  u16* ws = (u16*)d_ws;
  u16* Qws  = ws;              // 4194304
  u16* Kws  = ws + 4194304;    // 4194304
  u16* Vtws = ws + 8388608;    // 4194304
  u16* WoTw = ws + 12582912;   // 1048576
  u16* Wtws = ws + 13631488;   // 3145728
  u16* xtws = ws + 16777216;   // 4194304 (xt dead after k_qkvg)
  u16* Hdws = ws + 16777216;   // alias of xt

  k_prep<<<2048, 256, 0, stream>>>(x, Wq, Wk, Wv, Wo, xtws, Wtws, WoTw);
  k_qkvg<<<dim3(32, 24), 256, 0, stream>>>(xtws, Wtws, Qws, Kws, Vtws);
  k_attn<<<dim3(16, 16, 2), 512, 0, stream>>>(Qws, Kws, Vtws, mask, Hdws);
  k_projg<<<dim3(16, 32), 256, 0, stream>>>(WoTw, Hdws, (float*)d_out);
}

// Round 4
// 174.026 us; speedup vs baseline: 1.0641x; 1.0225x over previous
//
#include <hip/hip_runtime.h>
#include <hip/hip_bf16.h>

typedef unsigned short u16;
typedef unsigned int u32;
typedef unsigned long long u64;
typedef short s8v __attribute__((ext_vector_type(8)));
typedef short s4v __attribute__((ext_vector_type(4)));
typedef __bf16 bfv8 __attribute__((ext_vector_type(8)));
typedef float f4 __attribute__((ext_vector_type(4)));

static constexpr int B = 2, D = 1024, L = 2048, H = 16, DK = 64, E = 1024;
// fold 1/sqrt(DK) and log2(e) into Q so softmax runs natively in exp2 domain
static constexpr float QSCALE = 0.125f * 1.44269504088896340736f;
static constexpr float SMB = -16.0f;       // fixed softmax bias (|s|<~10)
static constexpr float MASKB = -12000.0f;  // exp2(MASKB+s) == 0.0f exactly

#define DEV __device__ __forceinline__

DEV u16 f2bf(float f) {  // fp32 -> bf16 round-to-nearest-even
  unsigned int u = __float_as_uint(f);
  u += 0x7FFFu + ((u >> 16) & 1u);
  return (u16)(u >> 16);
}
DEV float fexp2(float x) { return __builtin_amdgcn_exp2f(x); }
DEV u32 pkbf(float a, float b) {  // packed fp32x2 -> bf16x2 (v_cvt_pk)
  __hip_bfloat162 h = __float22bfloat162_rn(float2{a, b});
  u32 r;
  __builtin_memcpy(&r, &h, 4);
  return r;
}
DEV bfv8 cat8(s4v a, s4v b) {  // concat two 4x bf16 frags -> K=32 B-frag
  s8v r;
#pragma unroll
  for (int i = 0; i < 4; ++i) {
    r[i] = a[i];
    r[i + 4] = b[i];
  }
  return __builtin_bit_cast(bfv8, r);
}
// key-permutation: LDS kt row kk holds physical key kperm(kk).
// Within each 32-key group: row s*16+q*4+r -> key q*8+s*4+r, so that the
// QK^T output quads concat directly into K=32 PV B-frags over consecutive
// physical keys (V stays in natural order).  [verified in R1: 0 conflicts]
DEV int kperm(int kk) {
  return (kk & 96) | (((kk >> 2) & 3) << 3) | (((kk >> 4) & 1) << 2) |
         (kk & 3);
}

#define GLD_LDS16(gp, lp)                                                     \
  __builtin_amdgcn_global_load_lds(                                           \
      (const __attribute__((address_space(1))) void*)(gp),                    \
      (__attribute__((address_space(3))) void*)(lp), 16, 0, 0)

// ---------- Kernel 0: fused fp32->bf16 64x64 tile transposes ----------
__global__ __launch_bounds__(256) void k_prep(
    const float* __restrict__ x, const float* __restrict__ Wq,
    const float* __restrict__ Wk, const float* __restrict__ Wv,
    const float* __restrict__ Wo, u16* __restrict__ xt, u16* __restrict__ Wt,
    u16* __restrict__ WoT) {
  __shared__ u16 t[64][67];
  const int tid = threadIdx.x;
  const int g = blockIdx.x;
  const float* src;
  u16* dst;
  int sld, dld;
  if (g < 1024) {
    const int b = g >> 9, dt = (g >> 5) & 15, lt = g & 31;
    src = x + ((size_t)b * D + dt * 64) * L + lt * 64;
    sld = L;
    dst = xt + ((size_t)b * L + lt * 64) * D + dt * 64;
    dld = D;
  } else if (g < 1792) {
    const int u = g - 1024;
    const int w = u >> 8, h = (u >> 4) & 15, dt = u & 15;
    const float* Ws = (w == 0) ? Wq : ((w == 1) ? Wk : Wv);
    src = Ws + ((size_t)h * D + dt * 64) * DK;
    sld = DK;
    dst = Wt + ((size_t)(w * H + h) * DK) * D + dt * 64;
    dld = D;
  } else {
    const int v = g - 1792;
    const int et = v >> 4, dt = v & 15;
    src = Wo + ((size_t)et * 64) * D + dt * 64;
    sld = D;
    dst = WoT + ((size_t)dt * 64) * E + et * 64;
    dld = E;
  }
  const int r = tid >> 2, c16 = (tid & 3) * 16;
#pragma unroll
  for (int j = 0; j < 16; j += 4) {
    const f4 v4 = *(const f4*)(src + (size_t)r * sld + c16 + j);
    t[r][c16 + j]     = f2bf(v4[0]);
    t[r][c16 + j + 1] = f2bf(v4[1]);
    t[r][c16 + j + 2] = f2bf(v4[2]);
    t[r][c16 + j + 3] = f2bf(v4[3]);
  }
  __syncthreads();
  s8v o0, o1;
#pragma unroll
  for (int i = 0; i < 8; ++i) {
    o0[i] = (short)t[c16 + i][r];
    o1[i] = (short)t[c16 + 8 + i][r];
  }
  *(s8v*)(dst + (size_t)r * dld + c16)     = o0;
  *(s8v*)(dst + (size_t)r * dld + c16 + 8) = o1;
}

// ---------- shared GEMM tile core: BK=64, single-buffer, 1 barrier-pair ----
// LDS tiles [rows][64] u16 (128B rows), swizzle phys_chunk = logical^(row&7).
template <int AR>
DEV void gemm_tile(const u16* __restrict__ A, const u16* __restrict__ Bt,
                   int arow0, int brow0, u16* As, u16* Bs,
                   f4 (&acc)[AR / 32][4]) {
  const int tid = threadIdx.x;
  const int wid = tid >> 6, lane = tid & 63;
  const int q = lane >> 4, ln = lane & 15;
  const int wr = wid >> 1, wc = wid & 1;
  const int lrow = lane >> 3;        // 0..7 (dest row & 7)
  const int lc = (lane & 7) ^ lrow;  // logical chunk for swizzled dest
  const int f0 = (q ^ (ln & 7)) * 8;        // frag phys chunk, k-step 0
  const int f1 = ((q + 4) ^ (ln & 7)) * 8;  // k-step 1
  constexpr int MT = AR / 32;

  for (int k0 = 0; k0 < 1024; k0 += 64) {
    __syncthreads();
#pragma unroll
    for (int j = 0; j < AR / 32; ++j) {  // A: 8 rows per instr
      const int rb = wid * (AR / 4) + j * 8;
      GLD_LDS16(A + (size_t)(arow0 + rb + lrow) * 1024 + k0 + lc * 8,
                As + rb * 64);
    }
#pragma unroll
    for (int j = 0; j < 4; ++j) {  // B: 128 rows
      const int rb = wid * 32 + j * 8;
      GLD_LDS16(Bt + (size_t)(brow0 + rb + lrow) * 1024 + k0 + lc * 8,
                Bs + rb * 64);
    }
    __syncthreads();
#pragma unroll
    for (int ks = 0; ks < 2; ++ks) {
      const int fc = ks ? f1 : f0;
      bfv8 af[MT], bf[4];
#pragma unroll
      for (int mt = 0; mt < MT; ++mt)
        af[mt] = *(const bfv8*)(As + (wr * (AR / 2) + mt * 16 + ln) * 64 + fc);
#pragma unroll
      for (int nt = 0; nt < 4; ++nt)
        bf[nt] = *(const bfv8*)(Bs + (wc * 64 + nt * 16 + ln) * 64 + fc);
#pragma unroll
      for (int mt = 0; mt < MT; ++mt)
#pragma unroll
        for (int nt = 0; nt < 4; ++nt)
          acc[mt][nt] = __builtin_amdgcn_mfma_f32_16x16x32_bf16(
              af[mt], bf[nt], acc[mt][nt], 0, 0, 0);
    }
  }
}

// ---------- Kernel 1: QKV projection as one GEMM ----------
__global__ __launch_bounds__(256, 3) void k_qkvg(
    const u16* __restrict__ xt, const u16* __restrict__ Wt,
    u16* __restrict__ Q, u16* __restrict__ K, u16* __restrict__ Vt) {
  __shared__ u16 As[128 * 64];  // 16 KB
  __shared__ u16 Bs[128 * 64];  // 16 KB  (32 KB total: 3 blocks/CU ok)
  const int bm = blockIdx.x, bn = blockIdx.y;
  f4 acc[4][4];
#pragma unroll
  for (int mt = 0; mt < 4; ++mt)
#pragma unroll
    for (int nt = 0; nt < 4; ++nt) acc[mt][nt] = (f4){0.f, 0.f, 0.f, 0.f};
  gemm_tile<128>(xt, Wt, bm * 128, bn * 128, As, Bs, acc);

  const int tid = threadIdx.x, wid = tid >> 6, lane = tid & 63;
  const int q = lane >> 4, ln = lane & 15;
  const int wr = wid >> 1, wc = wid & 1;
  const int h2 = bn * 2 + wc;  // 0..47
  const int wsel = h2 >> 4, h = h2 & 15;
  const int b = bm >> 4;
  const int lbase = (bm & 15) * 128 + wr * 64;
  if (wsel == 0) {
    u16* dst = Q + (size_t)(b * H + h) * L * DK;
#pragma unroll
    for (int mt = 0; mt < 4; ++mt)
#pragma unroll
      for (int nt = 0; nt < 4; ++nt)
#pragma unroll
        for (int r = 0; r < 4; ++r)
          dst[(size_t)(lbase + mt * 16 + q * 4 + r) * DK + nt * 16 + ln] =
              f2bf(acc[mt][nt][r] * QSCALE);
  } else if (wsel == 1) {
    u16* dst = K + (size_t)(b * H + h) * L * DK;
#pragma unroll
    for (int mt = 0; mt < 4; ++mt)
#pragma unroll
      for (int nt = 0; nt < 4; ++nt)
#pragma unroll
        for (int r = 0; r < 4; ++r)
          dst[(size_t)(lbase + mt * 16 + q * 4 + r) * DK + nt * 16 + ln] =
              f2bf(acc[mt][nt][r]);
  } else {
    // V: plain transpose Vt[dk][l], 4 consecutive l per lane -> 8B stores
    u16* dst = Vt + (size_t)(b * H + h) * DK * L;
#pragma unroll
    for (int mt = 0; mt < 4; ++mt)
#pragma unroll
      for (int nt = 0; nt < 4; ++nt) {
        const u64 pk = (u64)pkbf(acc[mt][nt][0], acc[mt][nt][1]) |
                       ((u64)pkbf(acc[mt][nt][2], acc[mt][nt][3]) << 32);
        *(u64*)(dst + (size_t)(nt * 16 + ln) * L + lbase + mt * 16 + q * 4) =
            pk;
      }
  }
}

// ---------- Kernel 2: flash attention, 128-key tiles ----------
// R15: R1's conflict-free 16x16 mechanics + R3's wave geometry. 8 waves =
// 4 wq (32 q-rows via mt=0,1) x 2 wk (64-key halves). Every K/V fragment
// read is shared across 2 MFMAs -> half R1's LDS reads at 16 waves/CU,
// zero bank conflicts. Cross-wk O/lp reduction through LDS at the end.
__global__ __launch_bounds__(512, 4) void k_attn(
    const u16* __restrict__ Q, const u16* __restrict__ K,
    const u16* __restrict__ Vt, const float* __restrict__ mask,
    u16* __restrict__ Hd) {
  __shared__ u16 kt[2][128 * 64];    // [keyrow(permuted)][dk], chunk-swizzled
  __shared__ u16 vt[2][2][64 * 64];  // [half][dk][key(natural)], same swizzle
  __shared__ __align__(16) float mb[L];  // per-key bias: SMB or MASKB
  const int h = blockIdx.x, lt = blockIdx.y, b = blockIdx.z;
  const int tid = threadIdx.x;
  const int w = tid >> 6, lane = tid & 63, q = lane >> 4, ln = lane & 15;
  const int wq = w >> 1, wk = w & 1;
  for (int i = tid; i < L; i += 512)
    mb[i] = (mask[(size_t)b * L + i] != 0.0f) ? SMB : MASKB;

  const int bh = b * H + h;
  const u16* Qp = Q + (size_t)bh * L * DK;
  const u16* Kp = K + (size_t)bh * L * DK;
  const u16* Vp = Vt + (size_t)bh * DK * L;
  const int lq = lt * 128 + wq * 32;  // wave covers 32 q-rows (mt=0,1)

  bfv8 qf[2][2];
#pragma unroll
  for (int mt = 0; mt < 2; ++mt) {
    qf[mt][0] = *(const bfv8*)(Qp + (size_t)(lq + mt * 16 + ln) * DK + q * 8);
    qf[mt][1] =
        *(const bfv8*)(Qp + (size_t)(lq + mt * 16 + ln) * DK + 32 + q * 8);
  }

  const int lrow = lane >> 3;        // 0..7 (== dest row & 7)
  const int lc = (lane & 7) ^ lrow;  // logical chunk for swizzled dest
  const int c0 = (q ^ (ln & 7)) * 8;        // K-frag phys chunk, low dk half
  const int c1 = ((q + 4) ^ (ln & 7)) * 8;  // high dk half
  int kpr[2];  // permuted K source rows (loop-invariant)
#pragma unroll
  for (int j = 0; j < 2; ++j) kpr[j] = kperm(w * 16 + j * 8 + lrow);

  auto stage = [&](int m0, int bufi) {
    // kt: 128 rows, 8 waves x 16 rows, permuted key order
#pragma unroll
    for (int j = 0; j < 2; ++j) {
      GLD_LDS16(Kp + (size_t)(m0 + kpr[j]) * DK + lc * 8,
                &kt[bufi][(w * 16 + j * 8) * 64]);
    }
    // vt: per half 64 dk-rows, 8 waves x 8 rows, natural key order
    const int fr = w * 8 + lrow;
#pragma unroll
    for (int kh = 0; kh < 2; ++kh) {
      GLD_LDS16(Vp + (size_t)fr * L + m0 + kh * 64 + lc * 8,
                &vt[bufi][kh][(w * 8) * 64]);
    }
  };

  union {
    f4 v;
    float f[4];
  } ot[2][4];  // O^T[dk=dt*16+q*4+r][qrow=mt*16+ln], this wk's keys
#pragma unroll
  for (int mt = 0; mt < 2; ++mt)
#pragma unroll
    for (int dt = 0; dt < 4; ++dt) ot[mt][dt].v = (f4){0.f, 0.f, 0.f, 0.f};
  float lp[2] = {0.f, 0.f};  // per-mt partial row-sums (this quad+wk keys)

  stage(0, 0);
  for (int it = 0; it < L / 128; ++it) {
    const int m0 = it * 128;
    __syncthreads();  // buf(it&1) landed; mb ready; prev buf reads done
    if (it + 1 < L / 128) stage(m0 + 128, (it + 1) & 1);
    const int cur = it & 1;
    const u16* ktc = &kt[cur][0];
    const u16* vtc = &vt[cur][wk][0];  // this wk's 64 keys

    // QK^T swapped, fused exp2+pack; local strips nt over wk's 64 keys.
    s4v pbe[2];
    bfv8 pbx[2][2];
#pragma unroll
    for (int nt = 0; nt < 4; ++nt) {
      const int krow = wk * 64 + nt * 16 + ln;  // krow&7 == ln&7
      const bfv8 kf0 = *(const bfv8*)(ktc + krow * 64 + c0);
      const bfv8 kf1 = *(const bfv8*)(ktc + krow * 64 + c1);
      // mask bias at the PHYSICAL key held by this output quad
      const f4 mbv = *(const f4*)(mb + m0 + wk * 64 + (nt >> 1) * 32 +
                                  (nt & 1) * 4 + q * 8);
#pragma unroll
      for (int mt = 0; mt < 2; ++mt) {
        f4 a = mbv;  // mask bias in accumulator init
        __builtin_amdgcn_s_setprio(1);
        a = __builtin_amdgcn_mfma_f32_16x16x32_bf16(kf0, qf[mt][0], a, 0, 0,
                                                    0);
        a = __builtin_amdgcn_mfma_f32_16x16x32_bf16(kf1, qf[mt][1], a, 0, 0,
                                                    0);
        __builtin_amdgcn_s_setprio(0);
        const float p0 = fexp2(a[0]);  // masked keys: exact 0
        const float p1 = fexp2(a[1]);
        const float p2 = fexp2(a[2]);
        const float p3 = fexp2(a[3]);
        lp[mt] += (p0 + p1) + (p2 + p3);
        const u64 pk = (u64)pkbf(p0, p1) | ((u64)pkbf(p2, p3) << 32);
        const s4v pc = __builtin_bit_cast(s4v, pk);
        if (nt & 1)
          pbx[mt][nt >> 1] = cat8(pbe[mt], pc);
        else
          pbe[mt] = pc;
      }
    }
    // O^T += V^T . P^T on K=32 MFMA; V-frag shared across both mt
    __builtin_amdgcn_s_setprio(1);
#pragma unroll
    for (int g = 0; g < 2; ++g) {  // 32-key groups within wk's half
#pragma unroll
      for (int dt = 0; dt < 4; ++dt) {
        const int vrow = dt * 16 + ln;
        const bfv8 av =
            *(const bfv8*)(vtc + vrow * 64 + (((g * 4 + q) ^ (ln & 7)) * 8));
#pragma unroll
        for (int mt = 0; mt < 2; ++mt)
          ot[mt][dt].v = __builtin_amdgcn_mfma_f32_16x16x32_bf16(
              av, pbx[mt][g], ot[mt][dt].v, 0, 0, 0);
      }
    }
    __builtin_amdgcn_s_setprio(0);
  }
  // reduce across the 4 q-quads (same qrow) within the wave
#pragma unroll
  for (int mt = 0; mt < 2; ++mt) {
    lp[mt] += __shfl_xor(lp[mt], 16);
    lp[mt] += __shfl_xor(lp[mt], 32);
  }
  // cross-wk reduction through LDS scratch (kt/vt dead after last iter)
  __syncthreads();
  float* sOt = (float*)&kt[0][0];     // 32 KB: [wq][mt][dt][lane] f4
  float* sLp = (float*)&vt[0][0][0];  // 2 KB:  [wq][mt][lane]
  if (wk) {
#pragma unroll
    for (int mt = 0; mt < 2; ++mt) {
#pragma unroll
      for (int dt = 0; dt < 4; ++dt)
        *(f4*)(sOt + ((((wq * 2 + mt) * 4 + dt) * 64) + lane) * 4) =
            ot[mt][dt].v;
      sLp[(wq * 2 + mt) * 64 + lane] = lp[mt];
    }
  }
  __syncthreads();
  if (!wk) {
#pragma unroll
    for (int mt = 0; mt < 2; ++mt) {
#pragma unroll
      for (int dt = 0; dt < 4; ++dt)
        ot[mt][dt].v +=
            *(const f4*)(sOt + ((((wq * 2 + mt) * 4 + dt) * 64) + lane) * 4);
      lp[mt] += sLp[(wq * 2 + mt) * 64 + lane];
      const float linv =
          (mb[lq + mt * 16 + ln] > -100.0f) ? (1.0f / lp[mt]) : 0.0f;
#pragma unroll
      for (int dt = 0; dt < 4; ++dt) {
        const u64 pk =
            (u64)pkbf(ot[mt][dt].f[0] * linv, ot[mt][dt].f[1] * linv) |
            ((u64)pkbf(ot[mt][dt].f[2] * linv, ot[mt][dt].f[3] * linv) << 32);
        *(u64*)(Hd + (size_t)(b * L + lq + mt * 16 + ln) * E + h * DK +
                dt * 16 + q * 4) = pk;
      }
    }
  }
}

// ---------- Kernel 3: output projection as GEMM ----------
__global__ __launch_bounds__(256, 2) void k_projg(const u16* __restrict__ WoT,
                                                  const u16* __restrict__ Hd,
                                                  float* __restrict__ out) {
  __shared__ u16 As[64 * 64];   // 8 KB
  __shared__ u16 Bs[128 * 64];  // 16 KB
  const int bm = blockIdx.x, bn = blockIdx.y;
  f4 acc[2][4];
#pragma unroll
  for (int mt = 0; mt < 2; ++mt)
#pragma unroll
    for (int nt = 0; nt < 4; ++nt) acc[mt][nt] = (f4){0.f, 0.f, 0.f, 0.f};
  gemm_tile<64>(WoT, Hd, bm * 64, bn * 128, As, Bs, acc);

  const int tid = threadIdx.x, wid = tid >> 6, lane = tid & 63;
  const int q = lane >> 4, ln = lane & 15;
  const int wr = wid >> 1, wc = wid & 1;
#pragma unroll
  for (int mt = 0; mt < 2; ++mt)
#pragma unroll
    for (int nt = 0; nt < 4; ++nt)
#pragma unroll
      for (int r = 0; r < 4; ++r) {
        const int d = bm * 64 + wr * 32 + mt * 16 + q * 4 + r;
        const int n = bn * 128 + wc * 64 + nt * 16 + ln;
        const int bb = n >> 11, l = n & 2047;
        out[((size_t)(bb * D + d)) * L + l] = acc[mt][nt][r];
      }
}

extern "C" void kernel_launch(void* const* d_in, const int* in_sizes, int n_in,
                              void* d_out, int out_size, void* d_ws,
                              size_t ws_size, hipStream_t stream) {
  const float* x    = (const float*)d_in[0];
  const float* mask = (const float*)d_in[1];
  const float* Wq   = (const float*)d_in[2];
  const float* Wk   = (const float*)d_in[3];
  const float* Wv   = (const float*)d_in[4];
  const float* Wo   = (const float*)d_in[5];
  u16* ws = (u16*)d_ws;
  u16* Qws  = ws;              // 4194304
  u16* Kws  = ws + 4194304;    // 4194304
  u16* Vtws = ws + 8388608;    // 4194304
  u16* WoTw = ws + 12582912;   // 1048576
  u16* Wtws = ws + 13631488;   // 3145728
  u16* xtws = ws + 16777216;   // 4194304 (xt dead after k_qkvg)
  u16* Hdws = ws + 16777216;   // alias of xt

  k_prep<<<2048, 256, 0, stream>>>(x, Wq, Wk, Wv, Wo, xtws, Wtws, WoTw);
  k_qkvg<<<dim3(32, 24), 256, 0, stream>>>(xtws, Wtws, Qws, Kws, Vtws);
  k_attn<<<dim3(16, 16, 2), 512, 0, stream>>>(Qws, Kws, Vtws, mask, Hdws);
  k_projg<<<dim3(16, 32), 256, 0, stream>>>(WoTw, Hdws, (float*)d_out);
}

// Round 5
// 168.418 us; speedup vs baseline: 1.0995x; 1.0333x over previous
//
#include <hip/hip_runtime.h>
#include <hip/hip_bf16.h>

typedef unsigned short u16;
typedef unsigned int u32;
typedef unsigned long long u64;
typedef short s8v __attribute__((ext_vector_type(8)));
typedef short s4v __attribute__((ext_vector_type(4)));
typedef __bf16 bfv8 __attribute__((ext_vector_type(8)));
typedef float f4 __attribute__((ext_vector_type(4)));

static constexpr int B = 2, D = 1024, L = 2048, H = 16, DK = 64, E = 1024;
// fold 1/sqrt(DK) and log2(e) into Q so softmax runs natively in exp2 domain
static constexpr float QSCALE = 0.125f * 1.44269504088896340736f;
static constexpr float SMB = -16.0f;       // fixed softmax bias (|s|<~10)
static constexpr float MASKB = -12000.0f;  // exp2(MASKB+s) == 0.0f exactly

#define DEV __device__ __forceinline__

DEV u16 f2bf(float f) {  // fp32 -> bf16 round-to-nearest-even
  unsigned int u = __float_as_uint(f);
  u += 0x7FFFu + ((u >> 16) & 1u);
  return (u16)(u >> 16);
}
DEV float fexp2(float x) { return __builtin_amdgcn_exp2f(x); }
DEV u32 pkbf(float a, float b) {  // packed fp32x2 -> bf16x2 (v_cvt_pk)
  __hip_bfloat162 h = __float22bfloat162_rn(float2{a, b});
  u32 r;
  __builtin_memcpy(&r, &h, 4);
  return r;
}
DEV bfv8 cat8(s4v a, s4v b) {  // concat two 4x bf16 frags -> K=32 B-frag
  s8v r;
#pragma unroll
  for (int i = 0; i < 4; ++i) {
    r[i] = a[i];
    r[i + 4] = b[i];
  }
  return __builtin_bit_cast(bfv8, r);
}
// key-permutation: LDS kt row kk holds physical key kperm(kk).
// Within each 32-key group: row s*16+q*4+r -> key q*8+s*4+r, so that the
// QK^T output quads concat directly into K=32 PV B-frags over consecutive
// physical keys (V stays in natural order).  [verified in R1/R4: 0 conflicts]
DEV int kperm(int kk) {
  return (kk & 96) | (((kk >> 2) & 3) << 3) | (((kk >> 4) & 1) << 2) |
         (kk & 3);
}

#define GLD_LDS16(gp, lp)                                                     \
  __builtin_amdgcn_global_load_lds(                                           \
      (const __attribute__((address_space(1))) void*)(gp),                    \
      (__attribute__((address_space(3))) void*)(lp), 16, 0, 0)

// ---------- Kernel 0: fused fp32->bf16 64x64 tile transposes ----------
__global__ __launch_bounds__(256) void k_prep(
    const float* __restrict__ x, const float* __restrict__ Wq,
    const float* __restrict__ Wk, const float* __restrict__ Wv,
    const float* __restrict__ Wo, u16* __restrict__ xt, u16* __restrict__ Wt,
    u16* __restrict__ WoT) {
  __shared__ u16 t[64][67];
  const int tid = threadIdx.x;
  const int g = blockIdx.x;
  const float* src;
  u16* dst;
  int sld, dld;
  if (g < 1024) {
    const int b = g >> 9, dt = (g >> 5) & 15, lt = g & 31;
    src = x + ((size_t)b * D + dt * 64) * L + lt * 64;
    sld = L;
    dst = xt + ((size_t)b * L + lt * 64) * D + dt * 64;
    dld = D;
  } else if (g < 1792) {
    const int u = g - 1024;
    const int w = u >> 8, h = (u >> 4) & 15, dt = u & 15;
    const float* Ws = (w == 0) ? Wq : ((w == 1) ? Wk : Wv);
    src = Ws + ((size_t)h * D + dt * 64) * DK;
    sld = DK;
    dst = Wt + ((size_t)(w * H + h) * DK) * D + dt * 64;
    dld = D;
  } else {
    const int v = g - 1792;
    const int et = v >> 4, dt = v & 15;
    src = Wo + ((size_t)et * 64) * D + dt * 64;
    sld = D;
    dst = WoT + ((size_t)dt * 64) * E + et * 64;
    dld = E;
  }
  const int r = tid >> 2, c16 = (tid & 3) * 16;
#pragma unroll
  for (int j = 0; j < 16; j += 4) {
    const f4 v4 = *(const f4*)(src + (size_t)r * sld + c16 + j);
    t[r][c16 + j]     = f2bf(v4[0]);
    t[r][c16 + j + 1] = f2bf(v4[1]);
    t[r][c16 + j + 2] = f2bf(v4[2]);
    t[r][c16 + j + 3] = f2bf(v4[3]);
  }
  __syncthreads();
  s8v o0, o1;
#pragma unroll
  for (int i = 0; i < 8; ++i) {
    o0[i] = (short)t[c16 + i][r];
    o1[i] = (short)t[c16 + 8 + i][r];
  }
  *(s8v*)(dst + (size_t)r * dld + c16)     = o0;
  *(s8v*)(dst + (size_t)r * dld + c16 + 8) = o1;
}

// ---------- shared GEMM tile core: BK=64, single-buffer, 1 barrier-pair ----
// LDS tiles [rows][64] u16 (128B rows), swizzle phys_chunk = logical^(row&7).
// 4 waves fixed (2 wr x 2 wc); per-wave output (AR/2) x (BR/2).
template <int AR, int BR>
DEV void gemm_tile(const u16* __restrict__ A, const u16* __restrict__ Bt,
                   int arow0, int brow0, u16* As, u16* Bs,
                   f4 (&acc)[AR / 32][BR / 32]) {
  const int tid = threadIdx.x;
  const int wid = tid >> 6, lane = tid & 63;
  const int q = lane >> 4, ln = lane & 15;
  const int wr = wid >> 1, wc = wid & 1;
  const int lrow = lane >> 3;        // 0..7 (dest row & 7)
  const int lc = (lane & 7) ^ lrow;  // logical chunk for swizzled dest
  const int f0 = (q ^ (ln & 7)) * 8;        // frag phys chunk, k-step 0
  const int f1 = ((q + 4) ^ (ln & 7)) * 8;  // k-step 1
  constexpr int MT = AR / 32, NT = BR / 32;

  for (int k0 = 0; k0 < 1024; k0 += 64) {
    __syncthreads();
#pragma unroll
    for (int j = 0; j < AR / 32; ++j) {  // A: 8 rows per instr
      const int rb = wid * (AR / 4) + j * 8;
      GLD_LDS16(A + (size_t)(arow0 + rb + lrow) * 1024 + k0 + lc * 8,
                As + rb * 64);
    }
#pragma unroll
    for (int j = 0; j < BR / 32; ++j) {  // B: 8 rows per instr
      const int rb = wid * (BR / 4) + j * 8;
      GLD_LDS16(Bt + (size_t)(brow0 + rb + lrow) * 1024 + k0 + lc * 8,
                Bs + rb * 64);
    }
    __syncthreads();
#pragma unroll
    for (int ks = 0; ks < 2; ++ks) {
      const int fc = ks ? f1 : f0;
      bfv8 af[MT], bf[NT];
#pragma unroll
      for (int mt = 0; mt < MT; ++mt)
        af[mt] = *(const bfv8*)(As + (wr * (AR / 2) + mt * 16 + ln) * 64 + fc);
#pragma unroll
      for (int nt = 0; nt < NT; ++nt)
        bf[nt] = *(const bfv8*)(Bs + (wc * (BR / 2) + nt * 16 + ln) * 64 + fc);
#pragma unroll
      for (int mt = 0; mt < MT; ++mt)
#pragma unroll
        for (int nt = 0; nt < NT; ++nt)
          acc[mt][nt] = __builtin_amdgcn_mfma_f32_16x16x32_bf16(
              af[mt], bf[nt], acc[mt][nt], 0, 0, 0);
    }
  }
}

// ---------- Kernel 1: QKV projection as one GEMM ----------
// R16: XCD-aware swizzle — 8x12 tile rect per XCD so co-XCD blocks share
// A-panels (2 MB) and B-tiles in the 4 MB per-XCD L2.
__global__ __launch_bounds__(256, 3) void k_qkvg(
    const u16* __restrict__ xt, const u16* __restrict__ Wt,
    u16* __restrict__ Q, u16* __restrict__ K, u16* __restrict__ Vt) {
  __shared__ u16 As[128 * 64];  // 16 KB
  __shared__ u16 Bs[128 * 64];  // 16 KB  (32 KB total: 3 blocks/CU ok)
  const int orig = blockIdx.x;  // 768 = 32 bm x 24 bn
  const int xcd = orig & 7, kk = orig >> 3;      // kk: 0..95
  const int bm = (xcd >> 1) * 8 + (kk & 7);      // 4 rect rows of 8
  const int bn = (xcd & 1) * 12 + (kk >> 3);     // 2 rect cols of 12
  f4 acc[4][4];
#pragma unroll
  for (int mt = 0; mt < 4; ++mt)
#pragma unroll
    for (int nt = 0; nt < 4; ++nt) acc[mt][nt] = (f4){0.f, 0.f, 0.f, 0.f};
  gemm_tile<128, 128>(xt, Wt, bm * 128, bn * 128, As, Bs, acc);

  const int tid = threadIdx.x, wid = tid >> 6, lane = tid & 63;
  const int q = lane >> 4, ln = lane & 15;
  const int wr = wid >> 1, wc = wid & 1;
  const int h2 = bn * 2 + wc;  // 0..47
  const int wsel = h2 >> 4, h = h2 & 15;
  const int b = bm >> 4;
  const int lbase = (bm & 15) * 128 + wr * 64;
  if (wsel == 0) {
    u16* dst = Q + (size_t)(b * H + h) * L * DK;
#pragma unroll
    for (int mt = 0; mt < 4; ++mt)
#pragma unroll
      for (int nt = 0; nt < 4; ++nt)
#pragma unroll
        for (int r = 0; r < 4; ++r)
          dst[(size_t)(lbase + mt * 16 + q * 4 + r) * DK + nt * 16 + ln] =
              f2bf(acc[mt][nt][r] * QSCALE);
  } else if (wsel == 1) {
    u16* dst = K + (size_t)(b * H + h) * L * DK;
#pragma unroll
    for (int mt = 0; mt < 4; ++mt)
#pragma unroll
      for (int nt = 0; nt < 4; ++nt)
#pragma unroll
        for (int r = 0; r < 4; ++r)
          dst[(size_t)(lbase + mt * 16 + q * 4 + r) * DK + nt * 16 + ln] =
              f2bf(acc[mt][nt][r]);
  } else {
    // V: plain transpose Vt[dk][l], 4 consecutive l per lane -> 8B stores
    u16* dst = Vt + (size_t)(b * H + h) * DK * L;
#pragma unroll
    for (int mt = 0; mt < 4; ++mt)
#pragma unroll
      for (int nt = 0; nt < 4; ++nt) {
        const u64 pk = (u64)pkbf(acc[mt][nt][0], acc[mt][nt][1]) |
                       ((u64)pkbf(acc[mt][nt][2], acc[mt][nt][3]) << 32);
        *(u64*)(dst + (size_t)(nt * 16 + ln) * L + lbase + mt * 16 + q * 4) =
            pk;
      }
  }
}

// ---------- Kernel 2: flash attention, 128-key tiles ----------
// R16: XCD-aware block swizzle — 4 (b,h) pairs per XCD so the KV slices a
// given XCD streams (4 x 1 MB) fit its 4 MB L2; staging reads that were
// L3-served become L2 hits. Compute structure unchanged from R4.
__global__ __launch_bounds__(512, 4) void k_attn(
    const u16* __restrict__ Q, const u16* __restrict__ K,
    const u16* __restrict__ Vt, const float* __restrict__ mask,
    u16* __restrict__ Hd) {
  __shared__ u16 kt[2][128 * 64];    // [keyrow(permuted)][dk], chunk-swizzled
  __shared__ u16 vt[2][2][64 * 64];  // [half][dk][key(natural)], same swizzle
  __shared__ __align__(16) float mb[L];  // per-key bias: SMB or MASKB
  const int orig = blockIdx.x;  // 512 = 32 bh x 16 lt
  const int xcd = orig & 7, kk2 = orig >> 3;  // kk2: 0..63
  const int bh = xcd * 4 + (kk2 >> 4);        // 0..31, 4 bh per XCD
  const int lt = kk2 & 15;
  const int b = bh >> 4, h = bh & 15;
  const int tid = threadIdx.x;
  const int w = tid >> 6, lane = tid & 63, q = lane >> 4, ln = lane & 15;
  const int wq = w >> 1, wk = w & 1;
  for (int i = tid; i < L; i += 512)
    mb[i] = (mask[(size_t)b * L + i] != 0.0f) ? SMB : MASKB;

  const u16* Qp = Q + (size_t)bh * L * DK;
  const u16* Kp = K + (size_t)bh * L * DK;
  const u16* Vp = Vt + (size_t)bh * DK * L;
  const int lq = lt * 128 + wq * 32;  // wave covers 32 q-rows (mt=0,1)

  bfv8 qf[2][2];
#pragma unroll
  for (int mt = 0; mt < 2; ++mt) {
    qf[mt][0] = *(const bfv8*)(Qp + (size_t)(lq + mt * 16 + ln) * DK + q * 8);
    qf[mt][1] =
        *(const bfv8*)(Qp + (size_t)(lq + mt * 16 + ln) * DK + 32 + q * 8);
  }

  const int lrow = lane >> 3;        // 0..7 (== dest row & 7)
  const int lc = (lane & 7) ^ lrow;  // logical chunk for swizzled dest
  const int c0 = (q ^ (ln & 7)) * 8;        // K-frag phys chunk, low dk half
  const int c1 = ((q + 4) ^ (ln & 7)) * 8;  // high dk half
  int kpr[2];  // permuted K source rows (loop-invariant)
#pragma unroll
  for (int j = 0; j < 2; ++j) kpr[j] = kperm(w * 16 + j * 8 + lrow);

  auto stage = [&](int m0, int bufi) {
    // kt: 128 rows, 8 waves x 16 rows, permuted key order
#pragma unroll
    for (int j = 0; j < 2; ++j) {
      GLD_LDS16(Kp + (size_t)(m0 + kpr[j]) * DK + lc * 8,
                &kt[bufi][(w * 16 + j * 8) * 64]);
    }
    // vt: per half 64 dk-rows, 8 waves x 8 rows, natural key order
    const int fr = w * 8 + lrow;
#pragma unroll
    for (int kh = 0; kh < 2; ++kh) {
      GLD_LDS16(Vp + (size_t)fr * L + m0 + kh * 64 + lc * 8,
                &vt[bufi][kh][(w * 8) * 64]);
    }
  };

  union {
    f4 v;
    float f[4];
  } ot[2][4];  // O^T[dk=dt*16+q*4+r][qrow=mt*16+ln], this wk's keys
#pragma unroll
  for (int mt = 0; mt < 2; ++mt)
#pragma unroll
    for (int dt = 0; dt < 4; ++dt) ot[mt][dt].v = (f4){0.f, 0.f, 0.f, 0.f};
  float lp[2] = {0.f, 0.f};  // per-mt partial row-sums (this quad+wk keys)

  stage(0, 0);
  for (int it = 0; it < L / 128; ++it) {
    const int m0 = it * 128;
    __syncthreads();  // buf(it&1) landed; mb ready; prev buf reads done
    if (it + 1 < L / 128) stage(m0 + 128, (it + 1) & 1);
    const int cur = it & 1;
    const u16* ktc = &kt[cur][0];
    const u16* vtc = &vt[cur][wk][0];  // this wk's 64 keys

    // QK^T swapped, fused exp2+pack; local strips nt over wk's 64 keys.
    s4v pbe[2];
    bfv8 pbx[2][2];
#pragma unroll
    for (int nt = 0; nt < 4; ++nt) {
      const int krow = wk * 64 + nt * 16 + ln;  // krow&7 == ln&7
      const bfv8 kf0 = *(const bfv8*)(ktc + krow * 64 + c0);
      const bfv8 kf1 = *(const bfv8*)(ktc + krow * 64 + c1);
      // mask bias at the PHYSICAL key held by this output quad
      const f4 mbv = *(const f4*)(mb + m0 + wk * 64 + (nt >> 1) * 32 +
                                  (nt & 1) * 4 + q * 8);
#pragma unroll
      for (int mt = 0; mt < 2; ++mt) {
        f4 a = mbv;  // mask bias in accumulator init
        __builtin_amdgcn_s_setprio(1);
        a = __builtin_amdgcn_mfma_f32_16x16x32_bf16(kf0, qf[mt][0], a, 0, 0,
                                                    0);
        a = __builtin_amdgcn_mfma_f32_16x16x32_bf16(kf1, qf[mt][1], a, 0, 0,
                                                    0);
        __builtin_amdgcn_s_setprio(0);
        const float p0 = fexp2(a[0]);  // masked keys: exact 0
        const float p1 = fexp2(a[1]);
        const float p2 = fexp2(a[2]);
        const float p3 = fexp2(a[3]);
        lp[mt] += (p0 + p1) + (p2 + p3);
        const u64 pk = (u64)pkbf(p0, p1) | ((u64)pkbf(p2, p3) << 32);
        const s4v pc = __builtin_bit_cast(s4v, pk);
        if (nt & 1)
          pbx[mt][nt >> 1] = cat8(pbe[mt], pc);
        else
          pbe[mt] = pc;
      }
    }
    // O^T += V^T . P^T on K=32 MFMA; V-frag shared across both mt
    __builtin_amdgcn_s_setprio(1);
#pragma unroll
    for (int g = 0; g < 2; ++g) {  // 32-key groups within wk's half
#pragma unroll
      for (int dt = 0; dt < 4; ++dt) {
        const int vrow = dt * 16 + ln;
        const bfv8 av =
            *(const bfv8*)(vtc + vrow * 64 + (((g * 4 + q) ^ (ln & 7)) * 8));
#pragma unroll
        for (int mt = 0; mt < 2; ++mt)
          ot[mt][dt].v = __builtin_amdgcn_mfma_f32_16x16x32_bf16(
              av, pbx[mt][g], ot[mt][dt].v, 0, 0, 0);
      }
    }
    __builtin_amdgcn_s_setprio(0);
  }
  // reduce across the 4 q-quads (same qrow) within the wave
#pragma unroll
  for (int mt = 0; mt < 2; ++mt) {
    lp[mt] += __shfl_xor(lp[mt], 16);
    lp[mt] += __shfl_xor(lp[mt], 32);
  }
  // cross-wk reduction through LDS scratch (kt/vt dead after last iter)
  __syncthreads();
  float* sOt = (float*)&kt[0][0];     // 32 KB: [wq][mt][dt][lane] f4
  float* sLp = (float*)&vt[0][0][0];  // 2 KB:  [wq][mt][lane]
  if (wk) {
#pragma unroll
    for (int mt = 0; mt < 2; ++mt) {
#pragma unroll
      for (int dt = 0; dt < 4; ++dt)
        *(f4*)(sOt + ((((wq * 2 + mt) * 4 + dt) * 64) + lane) * 4) =
            ot[mt][dt].v;
      sLp[(wq * 2 + mt) * 64 + lane] = lp[mt];
    }
  }
  __syncthreads();
  if (!wk) {
#pragma unroll
    for (int mt = 0; mt < 2; ++mt) {
#pragma unroll
      for (int dt = 0; dt < 4; ++dt)
        ot[mt][dt].v +=
            *(const f4*)(sOt + ((((wq * 2 + mt) * 4 + dt) * 64) + lane) * 4);
      lp[mt] += sLp[(wq * 2 + mt) * 64 + lane];
      const float linv =
          (mb[lq + mt * 16 + ln] > -100.0f) ? (1.0f / lp[mt]) : 0.0f;
#pragma unroll
      for (int dt = 0; dt < 4; ++dt) {
        const u64 pk =
            (u64)pkbf(ot[mt][dt].f[0] * linv, ot[mt][dt].f[1] * linv) |
            ((u64)pkbf(ot[mt][dt].f[2] * linv, ot[mt][dt].f[3] * linv) << 32);
        *(u64*)(Hd + (size_t)(b * L + lq + mt * 16 + ln) * E + h * DK +
                dt * 16 + q * 4) = pk;
      }
    }
  }
}

// ---------- Kernel 3: output projection as GEMM ----------
// R16: 64x64 tiles -> grid 1024, 4 blocks/CU, 16 waves/CU (was 8); XCD
// swizzle keeps whole WoT (2 MB) + 8 Hd-tiles (1 MB) in each XCD's L2.
__global__ __launch_bounds__(256, 4) void k_projg(const u16* __restrict__ WoT,
                                                  const u16* __restrict__ Hd,
                                                  float* __restrict__ out) {
  __shared__ u16 As[64 * 64];  // 8 KB
  __shared__ u16 Bs[64 * 64];  // 8 KB
  const int orig = blockIdx.x;  // 1024 = 16 bm x 64 bn
  const int xcd = orig & 7, kk = orig >> 3;  // kk: 0..127
  const int bm = kk & 15;
  const int bn = xcd * 8 + (kk >> 4);  // 8 bn per XCD
  f4 acc[2][2];
#pragma unroll
  for (int mt = 0; mt < 2; ++mt)
#pragma unroll
    for (int nt = 0; nt < 2; ++nt) acc[mt][nt] = (f4){0.f, 0.f, 0.f, 0.f};
  gemm_tile<64, 64>(WoT, Hd, bm * 64, bn * 64, As, Bs, acc);

  const int tid = threadIdx.x, wid = tid >> 6, lane = tid & 63;
  const int q = lane >> 4, ln = lane & 15;
  const int wr = wid >> 1, wc = wid & 1;
#pragma unroll
  for (int mt = 0; mt < 2; ++mt)
#pragma unroll
    for (int nt = 0; nt < 2; ++nt)
#pragma unroll
      for (int r = 0; r < 4; ++r) {
        const int d = bm * 64 + wr * 32 + mt * 16 + q * 4 + r;
        const int n = bn * 64 + wc * 32 + nt * 16 + ln;
        const int bb = n >> 11, l = n & 2047;
        out[((size_t)(bb * D + d)) * L + l] = acc[mt][nt][r];
      }
}

extern "C" void kernel_launch(void* const* d_in, const int* in_sizes, int n_in,
                              void* d_out, int out_size, void* d_ws,
                              size_t ws_size, hipStream_t stream) {
  const float* x    = (const float*)d_in[0];
  const float* mask = (const float*)d_in[1];
  const float* Wq   = (const float*)d_in[2];
  const float* Wk   = (const float*)d_in[3];
  const float* Wv   = (const float*)d_in[4];
  const float* Wo   = (const float*)d_in[5];
  u16* ws = (u16*)d_ws;
  u16* Qws  = ws;              // 4194304
  u16* Kws  = ws + 4194304;    // 4194304
  u16* Vtws = ws + 8388608;    // 4194304
  u16* WoTw = ws + 12582912;   // 1048576
  u16* Wtws = ws + 13631488;   // 3145728
  u16* xtws = ws + 16777216;   // 4194304 (xt dead after k_qkvg)
  u16* Hdws = ws + 16777216;   // alias of xt

  k_prep<<<2048, 256, 0, stream>>>(x, Wq, Wk, Wv, Wo, xtws, Wtws, WoTw);
  k_qkvg<<<768, 256, 0, stream>>>(xtws, Wtws, Qws, Kws, Vtws);
  k_attn<<<512, 512, 0, stream>>>(Qws, Kws, Vtws, mask, Hdws);
  k_projg<<<1024, 256, 0, stream>>>(WoTw, Hdws, (float*)d_out);
}